// Round 3
// baseline (2118.036 us; speedup 1.0000x reference)
//
#include <hip/hip_runtime.h>
#include <hip/hip_bf16.h>

// SmallGAT R3: bf16 activations (fp32 weights/softmax/accum), wave-per-node GAT,
// LDS-staged pool, one-pass scan, k-unrolled GEMM.

#define NEG_SLOPE 0.2f

__device__ __forceinline__ float lrelu(float x) { return x > 0.f ? x : NEG_SLOPE * x; }
__device__ __forceinline__ float bf2f(unsigned short u) { return __uint_as_float(((unsigned)u) << 16); }
__device__ __forceinline__ unsigned short f2bf(float f) {
    unsigned x = __float_as_uint(f);
    return (unsigned short)((x + 0x7fffu + ((x >> 16) & 1u)) >> 16);  // RNE
}

// ---------------- CSR build ----------------
__global__ void csr_hist(const int* __restrict__ ei, int* __restrict__ deg, int E) {
    int e = blockIdx.x * 256 + threadIdx.x;
    if (e < E) atomicAdd(&deg[ei[E + e]], 1);
}

// one-pass scan; node degree = deg[n] + 1 (self loop)
__global__ __launch_bounds__(1024) void scan_kernel(const int* __restrict__ deg, int* __restrict__ offs, int N) {
    __shared__ int sums[1024];
    int t = threadIdx.x;
    int PER = (N + 1023) >> 10;
    int base = t * PER;
    int tot = 0;
    for (int i = 0; i < PER; ++i) {
        int n = base + i;
        if (n < N) tot += deg[n] + 1;
    }
    sums[t] = tot;
    __syncthreads();
    for (int off = 1; off < 1024; off <<= 1) {
        int x = (t >= off) ? sums[t - off] : 0;
        __syncthreads();
        sums[t] += x;
        __syncthreads();
    }
    int run = sums[t] - tot;
    for (int i = 0; i < PER; ++i) {
        int n = base + i;
        if (n < N) {
            offs[n] = run;
            run += deg[n] + 1;
        }
    }
    if (t == 1023) offs[N] = sums[1023];
}

__global__ void csr_self_place(const int* __restrict__ offs, int* __restrict__ ssrc,
                               int* __restrict__ cursor, int N) {
    int n = blockIdx.x * 256 + threadIdx.x;
    if (n >= N) return;
    int o = offs[n];
    ssrc[o] = n;  // self-loop
    cursor[n] = o + 1;
}

__global__ void csr_scatter(const int* __restrict__ ei, int* __restrict__ cursor,
                            int* __restrict__ ssrc, int E) {
    int e = blockIdx.x * 256 + threadIdx.x;
    if (e >= E) return;
    int d = ei[E + e];
    int pos = atomicAdd(&cursor[d], 1);
    ssrc[pos] = ei[e];
}

// ---------------- dense: W transpose + GEMM ----------------
__global__ void transpose_w(const float* __restrict__ W, float* __restrict__ Wt) {
    int i = blockIdx.x * 256 + threadIdx.x;  // i = k*128 + n
    if (i >= 16384) return;
    int n = i & 127, k = i >> 7;
    Wt[i] = W[n * 128 + k];
}

#define GBM 32
// out[m][n] = sum_k A[m][k] * Wt[k][n]; A fp32 or bf16; out bf16
template <typename T>
__global__ __launch_bounds__(256) void gemm_kernel(const T* __restrict__ A, const float* __restrict__ Wt,
                                                   unsigned short* __restrict__ out, int M) {
    __shared__ float Ws[128 * 128];   // [k][n] 64KB
    __shared__ float As[GBM][128];    // 16KB
    int tid = threadIdx.x;
    int m0 = blockIdx.x * GBM;
    const float4* Wt4 = (const float4*)Wt;
    float4* Ws4 = (float4*)Ws;
#pragma unroll
    for (int i = 0; i < 16; ++i) Ws4[tid + i * 256] = Wt4[tid + i * 256];
    if constexpr (sizeof(T) == 4) {
#pragma unroll
        for (int i = 0; i < 4; ++i) {
            int j = tid + i * 256;   // float4 slot
            int r = j >> 5;
            int c4 = (j & 31) << 2;
            int m = m0 + r;
            float4 v = make_float4(0.f, 0.f, 0.f, 0.f);
            if (m < M) v = *(const float4*)((const float*)A + (size_t)m * 128 + c4);
            *(float4*)(&As[r][c4]) = v;
        }
    } else {
#pragma unroll
        for (int i = 0; i < 2; ++i) {
            int j = tid + i * 256;   // ushort8 slot (8 ch)
            int r = j >> 4;
            int c8 = (j & 15) << 3;
            int m = m0 + r;
            uint4 u = make_uint4(0, 0, 0, 0);
            if (m < M) u = *(const uint4*)((const unsigned short*)A + (size_t)m * 128 + c8);
            float* dst = &As[r][c8];
            dst[0] = __uint_as_float(u.x << 16); dst[1] = __uint_as_float(u.x & 0xffff0000u);
            dst[2] = __uint_as_float(u.y << 16); dst[3] = __uint_as_float(u.y & 0xffff0000u);
            dst[4] = __uint_as_float(u.z << 16); dst[5] = __uint_as_float(u.z & 0xffff0000u);
            dst[6] = __uint_as_float(u.w << 16); dst[7] = __uint_as_float(u.w & 0xffff0000u);
        }
    }
    __syncthreads();
    int rg = tid >> 5;  // rows rg*4..rg*4+3
    int ct = tid & 31;  // cols ct*4..ct*4+3
    float acc[4][4] = {{0.f}};
#pragma unroll
    for (int k4 = 0; k4 < 32; ++k4) {
        float4 a0 = *(const float4*)(&As[rg * 4 + 0][k4 * 4]);
        float4 a1 = *(const float4*)(&As[rg * 4 + 1][k4 * 4]);
        float4 a2 = *(const float4*)(&As[rg * 4 + 2][k4 * 4]);
        float4 a3 = *(const float4*)(&As[rg * 4 + 3][k4 * 4]);
#pragma unroll
        for (int kk = 0; kk < 4; ++kk) {
            float4 b = *(const float4*)(&Ws[(k4 * 4 + kk) * 128 + ct * 4]);
            float e0 = (&a0.x)[kk], e1 = (&a1.x)[kk], e2 = (&a2.x)[kk], e3 = (&a3.x)[kk];
            acc[0][0] += e0 * b.x; acc[0][1] += e0 * b.y; acc[0][2] += e0 * b.z; acc[0][3] += e0 * b.w;
            acc[1][0] += e1 * b.x; acc[1][1] += e1 * b.y; acc[1][2] += e1 * b.z; acc[1][3] += e1 * b.w;
            acc[2][0] += e2 * b.x; acc[2][1] += e2 * b.y; acc[2][2] += e2 * b.z; acc[2][3] += e2 * b.w;
            acc[3][0] += e3 * b.x; acc[3][1] += e3 * b.y; acc[3][2] += e3 * b.z; acc[3][3] += e3 * b.w;
        }
    }
#pragma unroll
    for (int i = 0; i < 4; ++i) {
        int m = m0 + rg * 4 + i;
        if (m < M) {
            unsigned lo = (unsigned)f2bf(acc[i][0]) | ((unsigned)f2bf(acc[i][1]) << 16);
            unsigned hi = (unsigned)f2bf(acc[i][2]) | ((unsigned)f2bf(acc[i][3]) << 16);
            *(uint2*)(out + (size_t)m * 128 + ct * 4) = make_uint2(lo, hi);
        }
    }
}

// ---------------- attention dots (wave per node) ----------------
__global__ __launch_bounds__(256) void att_kernel(const unsigned short* __restrict__ XLb,
                                                  const float* __restrict__ att_s, const float* __restrict__ att_d,
                                                  float* __restrict__ a_src, float* __restrict__ a_dst, int N) {
    int t = threadIdx.x;
    int l = t & 63;
    int n = blockIdx.x * 4 + (t >> 6);
    if (n >= N) return;
    int c = 2 * l;
    unsigned u = *(const unsigned*)(XLb + (size_t)n * 128 + c);
    float f0 = __uint_as_float(u << 16);
    float f1 = __uint_as_float(u & 0xffff0000u);
    float ps = f0 * att_s[c] + f1 * att_s[c + 1];
    float pd = f0 * att_d[c] + f1 * att_d[c + 1];
#pragma unroll
    for (int off = 16; off > 0; off >>= 1) {
        ps += __shfl_xor(ps, off);
        pd += __shfl_xor(pd, off);
    }
    if ((l & 31) == 0) {
        int h = l >> 5;
        a_src[n * 2 + h] = ps;
        a_dst[n * 2 + h] = pd;
    }
}

// ---------------- fused per-node softmax + aggregate (wave per node) ----------------
// lane l: channels 2l,2l+1; head h = l>>5. Half-wave (32 lanes) covers all edges of its head.
#define MAXD 128
__global__ __launch_bounds__(256) void gat_node_kernel(const unsigned short* __restrict__ XLb,
                                                       const float* __restrict__ a_src, const float* __restrict__ a_dst,
                                                       const int* __restrict__ offs, const int* __restrict__ ssrc,
                                                       const float* __restrict__ bias,
                                                       unsigned short* __restrict__ out, int N) {
    __shared__ float coeff[4][2][MAXD];
    __shared__ int srcs[4][MAXD];
    int t = threadIdx.x;
    int w = t >> 6, l = t & 63;
    int n = blockIdx.x * 4 + w;
    if (n >= N) return;
    int h = l >> 5, sl = l & 31;
    int c = 2 * l;
    int j0 = offs[n], j1 = offs[n + 1];
    int deg = j1 - j0;
    float ad = a_dst[n * 2 + h];
    float acc0 = 0.f, acc1 = 0.f;
    if (deg <= MAXD) {
        float m = -1e30f;
        for (int k = sl; k < deg; k += 32) {
            int s = ssrc[j0 + k];
            if (h == 0) srcs[w][k] = s;
            float al = lrelu(a_src[s * 2 + h] + ad);
            coeff[w][h][k] = al;
            m = fmaxf(m, al);
        }
#pragma unroll
        for (int off = 16; off > 0; off >>= 1) m = fmaxf(m, __shfl_xor(m, off));
        float sum = 0.f;
        for (int k = sl; k < deg; k += 32) {
            float e = __expf(coeff[w][h][k] - m);
            coeff[w][h][k] = e;
            sum += e;
        }
#pragma unroll
        for (int off = 16; off > 0; off >>= 1) sum += __shfl_xor(sum, off);
        float inv = 1.f / fmaxf(sum, 1e-16f);
        int j = 0;
        for (; j + 1 < deg; j += 2) {
            float c0 = coeff[w][h][j] * inv;
            float c1 = coeff[w][h][j + 1] * inv;
            int s0 = srcs[w][j];
            int s1 = srcs[w][j + 1];
            unsigned u0 = *(const unsigned*)(XLb + (size_t)s0 * 128 + c);
            unsigned u1 = *(const unsigned*)(XLb + (size_t)s1 * 128 + c);
            acc0 += c0 * __uint_as_float(u0 << 16) + c1 * __uint_as_float(u1 << 16);
            acc1 += c0 * __uint_as_float(u0 & 0xffff0000u) + c1 * __uint_as_float(u1 & 0xffff0000u);
        }
        if (j < deg) {
            float c0 = coeff[w][h][j] * inv;
            int s0 = srcs[w][j];
            unsigned u0 = *(const unsigned*)(XLb + (size_t)s0 * 128 + c);
            acc0 += c0 * __uint_as_float(u0 << 16);
            acc1 += c0 * __uint_as_float(u0 & 0xffff0000u);
        }
    } else {
        // streaming fallback (recompute), deg > MAXD
        float m = -1e30f;
        for (int k = sl; k < deg; k += 32) {
            int s = ssrc[j0 + k];
            m = fmaxf(m, lrelu(a_src[s * 2 + h] + ad));
        }
#pragma unroll
        for (int off = 16; off > 0; off >>= 1) m = fmaxf(m, __shfl_xor(m, off));
        float sum = 0.f;
        for (int k = sl; k < deg; k += 32) {
            int s = ssrc[j0 + k];
            sum += __expf(lrelu(a_src[s * 2 + h] + ad) - m);
        }
#pragma unroll
        for (int off = 16; off > 0; off >>= 1) sum += __shfl_xor(sum, off);
        float inv = 1.f / fmaxf(sum, 1e-16f);
        for (int j = 0; j < deg; ++j) {
            int s = ssrc[j0 + j];
            float cc = __expf(lrelu(a_src[s * 2 + h] + ad) - m) * inv;
            unsigned u0 = *(const unsigned*)(XLb + (size_t)s * 128 + c);
            acc0 += cc * __uint_as_float(u0 << 16);
            acc1 += cc * __uint_as_float(u0 & 0xffff0000u);
        }
    }
    float o0 = fmaxf(acc0 + bias[c], 0.f);
    float o1 = fmaxf(acc1 + bias[c + 1], 0.f);
    *(unsigned*)(out + (size_t)n * 128 + c) = (unsigned)f2bf(o0) | ((unsigned)f2bf(o1) << 16);
}

// ---------------- pooling (LDS-staged) + FC ----------------
#define PB 128
__global__ __launch_bounds__(128) void pool_kernel(const unsigned short* __restrict__ Hb,
                                                   const int* __restrict__ batch,
                                                   float* __restrict__ pooled, int* __restrict__ counts, int N) {
    __shared__ unsigned short Hs[PB * 128];
    __shared__ int bs[PB];
    int t = threadIdx.x;
    int base = blockIdx.x * PB;
    int lim = min(PB, N - base);
    // stage: PB rows x 128 ch as uint4 (8 ushorts); 2048 slots / 128 threads = 16 iters
#pragma unroll
    for (int i = 0; i < 16; ++i) {
        int slot = i * 128 + t;
        int r = slot >> 4;
        int c8 = (slot & 15) << 3;
        uint4 u = make_uint4(0, 0, 0, 0);
        int n0 = base + r;
        if (n0 < N) u = *(const uint4*)(Hb + (size_t)n0 * 128 + c8);
        *(uint4*)(&Hs[r * 128 + c8]) = u;
    }
    if (t < lim) bs[t] = batch[base + t];
    __syncthreads();
    float acc = 0.f;
    int cur = bs[0];
    int runstart = 0;
    for (int i = 0; i < lim; ++i) {
        int g = bs[i];
        if (g != cur) {
            atomicAdd(&pooled[cur * 128 + t], acc);
            if (t == 0) atomicAdd(&counts[cur], i - runstart);
            cur = g;
            acc = 0.f;
            runstart = i;
        }
        acc += bf2f(Hs[i * 128 + t]);
    }
    atomicAdd(&pooled[cur * 128 + t], acc);
    if (t == 0) atomicAdd(&counts[cur], lim - runstart);
}

__global__ void final_kernel(const float* __restrict__ pooled, const int* __restrict__ counts,
                             const float* __restrict__ fc_w, const float* __restrict__ fc_b,
                             float* __restrict__ out) {
    int idx = blockIdx.x * 256 + threadIdx.x;
    if (idx >= 64 * 32) return;
    int g = idx >> 5, k = idx & 31;
    float invc = 1.f / fmaxf((float)counts[g], 1.f);
    float s = 0.f;
#pragma unroll 4
    for (int c = 0; c < 128; ++c) s += pooled[g * 128 + c] * fc_w[k * 128 + c];
    out[idx] = s * invc + fc_b[k];
}

// ---------------- host ----------------
extern "C" void kernel_launch(void* const* d_in, const int* in_sizes, int n_in,
                              void* d_out, int out_size, void* d_ws, size_t ws_size,
                              hipStream_t stream) {
    const float* x = (const float*)d_in[0];
    const int* ei = (const int*)d_in[1];
    const int* batch = (const int*)d_in[2];
    const float* W1 = (const float*)d_in[3];
    const float* as1 = (const float*)d_in[4];
    const float* ad1 = (const float*)d_in[5];
    const float* b1 = (const float*)d_in[6];
    const float* W2 = (const float*)d_in[7];
    const float* as2 = (const float*)d_in[8];
    const float* ad2 = (const float*)d_in[9];
    const float* b2 = (const float*)d_in[10];
    const float* fcw = (const float*)d_in[11];
    const float* fcb = (const float*)d_in[12];
    float* out = (float*)d_out;

    const int N = in_sizes[0] / 128;  // 50000
    const int E = in_sizes[1] / 2;    // 800000
    const int EN = E + N;

    char* p = (char*)d_ws;
    auto alloc = [&](size_t bytes) -> char* {
        char* r = p;
        p += (bytes + 255) & ~(size_t)255;
        return r;
    };
    unsigned short* XLb = (unsigned short*)alloc((size_t)N * 128 * 2);
    unsigned short* Hb = (unsigned short*)alloc((size_t)N * 128 * 2);
    float* a_src = (float*)alloc((size_t)N * 2 * 4);
    float* a_dst = (float*)alloc((size_t)N * 2 * 4);
    int* deg = (int*)alloc((size_t)N * 4);
    int* offs = (int*)alloc((size_t)(N + 1) * 4);
    int* cursor = (int*)alloc((size_t)N * 4);
    int* ssrc = (int*)alloc((size_t)EN * 4);
    float* Wt = (float*)alloc(16384 * 4);
    float* pooled = (float*)alloc(8192 * 4);
    int* counts = (int*)alloc(64 * 4);

    const int TB = 256;
    int gN = (N + TB - 1) / TB;
    int gE = (E + TB - 1) / TB;
    int gGemm = (N + GBM - 1) / GBM;
    int gWave = (N + 3) / 4;

    // CSR build (shared by both layers)
    hipMemsetAsync(deg, 0, (size_t)N * 4, stream);
    csr_hist<<<gE, TB, 0, stream>>>(ei, deg, E);
    scan_kernel<<<1, 1024, 0, stream>>>(deg, offs, N);
    csr_self_place<<<gN, TB, 0, stream>>>(offs, ssrc, cursor, N);
    csr_scatter<<<gE, TB, 0, stream>>>(ei, cursor, ssrc, E);

    // ---- layer 1 ----
    transpose_w<<<64, TB, 0, stream>>>(W1, Wt);
    gemm_kernel<float><<<gGemm, TB, 0, stream>>>(x, Wt, XLb, N);
    att_kernel<<<gWave, TB, 0, stream>>>(XLb, as1, ad1, a_src, a_dst, N);
    gat_node_kernel<<<gWave, TB, 0, stream>>>(XLb, a_src, a_dst, offs, ssrc, b1, Hb, N);

    // ---- layer 2 ----
    transpose_w<<<64, TB, 0, stream>>>(W2, Wt);
    gemm_kernel<unsigned short><<<gGemm, TB, 0, stream>>>(Hb, Wt, XLb, N);
    att_kernel<<<gWave, TB, 0, stream>>>(XLb, as2, ad2, a_src, a_dst, N);
    gat_node_kernel<<<gWave, TB, 0, stream>>>(XLb, a_src, a_dst, offs, ssrc, b2, Hb, N);

    // ---- pool + FC ----
    hipMemsetAsync(pooled, 0, 8192 * 4 + 256, stream);
    pool_kernel<<<(N + PB - 1) / PB, 128, 0, stream>>>(Hb, batch, pooled, counts, N);
    final_kernel<<<8, TB, 0, stream>>>(pooled, counts, fcw, fcb, out);
}

// Round 4
// 473.022 us; speedup vs baseline: 4.4777x; 4.4777x over previous
//
#include <hip/hip_runtime.h>
#include <hip/hip_bf16.h>

// SmallGAT R4: R3 minus the GEMM scratch-spill (no address-taken vector indexing).
// bf16 activations (fp32 weights/softmax/accum), wave-per-node GAT, LDS-staged pool.

#define NEG_SLOPE 0.2f

__device__ __forceinline__ float lrelu(float x) { return x > 0.f ? x : NEG_SLOPE * x; }
__device__ __forceinline__ float bf2f(unsigned short u) { return __uint_as_float(((unsigned)u) << 16); }
__device__ __forceinline__ unsigned short f2bf(float f) {
    unsigned x = __float_as_uint(f);
    return (unsigned short)((x + 0x7fffu + ((x >> 16) & 1u)) >> 16);  // RNE
}

// ---------------- CSR build ----------------
__global__ void csr_hist(const int* __restrict__ ei, int* __restrict__ deg, int E) {
    int e = blockIdx.x * 256 + threadIdx.x;
    if (e < E) atomicAdd(&deg[ei[E + e]], 1);
}

// one-pass scan; node degree = deg[n] + 1 (self loop)
__global__ __launch_bounds__(1024) void scan_kernel(const int* __restrict__ deg, int* __restrict__ offs, int N) {
    __shared__ int sums[1024];
    int t = threadIdx.x;
    int PER = (N + 1023) >> 10;
    int base = t * PER;
    int tot = 0;
    for (int i = 0; i < PER; ++i) {
        int n = base + i;
        if (n < N) tot += deg[n] + 1;
    }
    sums[t] = tot;
    __syncthreads();
    for (int off = 1; off < 1024; off <<= 1) {
        int x = (t >= off) ? sums[t - off] : 0;
        __syncthreads();
        sums[t] += x;
        __syncthreads();
    }
    int run = sums[t] - tot;
    for (int i = 0; i < PER; ++i) {
        int n = base + i;
        if (n < N) {
            offs[n] = run;
            run += deg[n] + 1;
        }
    }
    if (t == 1023) offs[N] = sums[1023];
}

__global__ void csr_self_place(const int* __restrict__ offs, int* __restrict__ ssrc,
                               int* __restrict__ cursor, int N) {
    int n = blockIdx.x * 256 + threadIdx.x;
    if (n >= N) return;
    int o = offs[n];
    ssrc[o] = n;  // self-loop
    cursor[n] = o + 1;
}

__global__ void csr_scatter(const int* __restrict__ ei, int* __restrict__ cursor,
                            int* __restrict__ ssrc, int E) {
    int e = blockIdx.x * 256 + threadIdx.x;
    if (e >= E) return;
    int d = ei[E + e];
    int pos = atomicAdd(&cursor[d], 1);
    ssrc[pos] = ei[e];
}

// ---------------- dense: W transpose + GEMM ----------------
__global__ void transpose_w(const float* __restrict__ W, float* __restrict__ Wt) {
    int i = blockIdx.x * 256 + threadIdx.x;  // i = k*128 + n
    if (i >= 16384) return;
    int n = i & 127, k = i >> 7;
    Wt[i] = W[n * 128 + k];
}

#define GBM 32
// out[m][n] = sum_k A[m][k] * Wt[k][n]; A fp32 or bf16; out bf16
template <typename T>
__global__ __launch_bounds__(256) void gemm_kernel(const T* __restrict__ A, const float* __restrict__ Wt,
                                                   unsigned short* __restrict__ out, int M) {
    __shared__ float Ws[128 * 128];   // [k][n] 64KB
    __shared__ float As[GBM][128];    // 16KB
    int tid = threadIdx.x;
    int m0 = blockIdx.x * GBM;
    const float4* Wt4 = (const float4*)Wt;
    float4* Ws4 = (float4*)Ws;
#pragma unroll
    for (int i = 0; i < 16; ++i) Ws4[tid + i * 256] = Wt4[tid + i * 256];
    if constexpr (sizeof(T) == 4) {
#pragma unroll
        for (int i = 0; i < 4; ++i) {
            int j = tid + i * 256;   // float4 slot
            int r = j >> 5;
            int c4 = (j & 31) << 2;
            int m = m0 + r;
            float4 v = make_float4(0.f, 0.f, 0.f, 0.f);
            if (m < M) v = *(const float4*)((const float*)A + (size_t)m * 128 + c4);
            *(float4*)(&As[r][c4]) = v;
        }
    } else {
#pragma unroll
        for (int i = 0; i < 2; ++i) {
            int j = tid + i * 256;   // ushort8 slot (8 ch)
            int r = j >> 4;
            int c8 = (j & 15) << 3;
            int m = m0 + r;
            uint4 u = make_uint4(0, 0, 0, 0);
            if (m < M) u = *(const uint4*)((const unsigned short*)A + (size_t)m * 128 + c8);
            float* dst = &As[r][c8];
            dst[0] = __uint_as_float(u.x << 16); dst[1] = __uint_as_float(u.x & 0xffff0000u);
            dst[2] = __uint_as_float(u.y << 16); dst[3] = __uint_as_float(u.y & 0xffff0000u);
            dst[4] = __uint_as_float(u.z << 16); dst[5] = __uint_as_float(u.z & 0xffff0000u);
            dst[6] = __uint_as_float(u.w << 16); dst[7] = __uint_as_float(u.w & 0xffff0000u);
        }
    }
    __syncthreads();
    int rg = tid >> 5;  // rows rg*4..rg*4+3
    int ct = tid & 31;  // cols ct*4..ct*4+3
    float acc[4][4] = {{0.f}};
#pragma unroll 4
    for (int k = 0; k < 128; ++k) {
        float4 b = *(const float4*)(&Ws[k * 128 + ct * 4]);
        float a0 = As[rg * 4 + 0][k];
        float a1 = As[rg * 4 + 1][k];
        float a2 = As[rg * 4 + 2][k];
        float a3 = As[rg * 4 + 3][k];
        acc[0][0] += a0 * b.x; acc[0][1] += a0 * b.y; acc[0][2] += a0 * b.z; acc[0][3] += a0 * b.w;
        acc[1][0] += a1 * b.x; acc[1][1] += a1 * b.y; acc[1][2] += a1 * b.z; acc[1][3] += a1 * b.w;
        acc[2][0] += a2 * b.x; acc[2][1] += a2 * b.y; acc[2][2] += a2 * b.z; acc[2][3] += a2 * b.w;
        acc[3][0] += a3 * b.x; acc[3][1] += a3 * b.y; acc[3][2] += a3 * b.z; acc[3][3] += a3 * b.w;
    }
#pragma unroll
    for (int i = 0; i < 4; ++i) {
        int m = m0 + rg * 4 + i;
        if (m < M) {
            unsigned lo = (unsigned)f2bf(acc[i][0]) | ((unsigned)f2bf(acc[i][1]) << 16);
            unsigned hi = (unsigned)f2bf(acc[i][2]) | ((unsigned)f2bf(acc[i][3]) << 16);
            *(uint2*)(out + (size_t)m * 128 + ct * 4) = make_uint2(lo, hi);
        }
    }
}

// ---------------- attention dots (wave per node) ----------------
__global__ __launch_bounds__(256) void att_kernel(const unsigned short* __restrict__ XLb,
                                                  const float* __restrict__ att_s, const float* __restrict__ att_d,
                                                  float* __restrict__ a_src, float* __restrict__ a_dst, int N) {
    int t = threadIdx.x;
    int l = t & 63;
    int n = blockIdx.x * 4 + (t >> 6);
    if (n >= N) return;
    int c = 2 * l;
    unsigned u = *(const unsigned*)(XLb + (size_t)n * 128 + c);
    float f0 = __uint_as_float(u << 16);
    float f1 = __uint_as_float(u & 0xffff0000u);
    float ps = f0 * att_s[c] + f1 * att_s[c + 1];
    float pd = f0 * att_d[c] + f1 * att_d[c + 1];
#pragma unroll
    for (int off = 16; off > 0; off >>= 1) {
        ps += __shfl_xor(ps, off);
        pd += __shfl_xor(pd, off);
    }
    if ((l & 31) == 0) {
        int h = l >> 5;
        a_src[n * 2 + h] = ps;
        a_dst[n * 2 + h] = pd;
    }
}

// ---------------- fused per-node softmax + aggregate (wave per node) ----------------
// lane l: channels 2l,2l+1; head h = l>>5. Half-wave (32 lanes) covers all edges of its head.
#define MAXD 128
__global__ __launch_bounds__(256) void gat_node_kernel(const unsigned short* __restrict__ XLb,
                                                       const float* __restrict__ a_src, const float* __restrict__ a_dst,
                                                       const int* __restrict__ offs, const int* __restrict__ ssrc,
                                                       const float* __restrict__ bias,
                                                       unsigned short* __restrict__ out, int N) {
    __shared__ float coeff[4][2][MAXD];
    __shared__ int srcs[4][MAXD];
    int t = threadIdx.x;
    int w = t >> 6, l = t & 63;
    int n = blockIdx.x * 4 + w;
    if (n >= N) return;
    int h = l >> 5, sl = l & 31;
    int c = 2 * l;
    int j0 = offs[n], j1 = offs[n + 1];
    int deg = j1 - j0;
    float ad = a_dst[n * 2 + h];
    float acc0 = 0.f, acc1 = 0.f;
    if (deg <= MAXD) {
        float m = -1e30f;
        for (int k = sl; k < deg; k += 32) {
            int s = ssrc[j0 + k];
            if (h == 0) srcs[w][k] = s;
            float al = lrelu(a_src[s * 2 + h] + ad);
            coeff[w][h][k] = al;
            m = fmaxf(m, al);
        }
#pragma unroll
        for (int off = 16; off > 0; off >>= 1) m = fmaxf(m, __shfl_xor(m, off));
        float sum = 0.f;
        for (int k = sl; k < deg; k += 32) {
            float e = __expf(coeff[w][h][k] - m);
            coeff[w][h][k] = e;
            sum += e;
        }
#pragma unroll
        for (int off = 16; off > 0; off >>= 1) sum += __shfl_xor(sum, off);
        float inv = 1.f / fmaxf(sum, 1e-16f);
        int j = 0;
        for (; j + 1 < deg; j += 2) {
            float c0 = coeff[w][h][j] * inv;
            float c1 = coeff[w][h][j + 1] * inv;
            int s0 = srcs[w][j];
            int s1 = srcs[w][j + 1];
            unsigned u0 = *(const unsigned*)(XLb + (size_t)s0 * 128 + c);
            unsigned u1 = *(const unsigned*)(XLb + (size_t)s1 * 128 + c);
            acc0 += c0 * __uint_as_float(u0 << 16) + c1 * __uint_as_float(u1 << 16);
            acc1 += c0 * __uint_as_float(u0 & 0xffff0000u) + c1 * __uint_as_float(u1 & 0xffff0000u);
        }
        if (j < deg) {
            float c0 = coeff[w][h][j] * inv;
            int s0 = srcs[w][j];
            unsigned u0 = *(const unsigned*)(XLb + (size_t)s0 * 128 + c);
            acc0 += c0 * __uint_as_float(u0 << 16);
            acc1 += c0 * __uint_as_float(u0 & 0xffff0000u);
        }
    } else {
        // streaming fallback (recompute), deg > MAXD
        float m = -1e30f;
        for (int k = sl; k < deg; k += 32) {
            int s = ssrc[j0 + k];
            m = fmaxf(m, lrelu(a_src[s * 2 + h] + ad));
        }
#pragma unroll
        for (int off = 16; off > 0; off >>= 1) m = fmaxf(m, __shfl_xor(m, off));
        float sum = 0.f;
        for (int k = sl; k < deg; k += 32) {
            int s = ssrc[j0 + k];
            sum += __expf(lrelu(a_src[s * 2 + h] + ad) - m);
        }
#pragma unroll
        for (int off = 16; off > 0; off >>= 1) sum += __shfl_xor(sum, off);
        float inv = 1.f / fmaxf(sum, 1e-16f);
        for (int j = 0; j < deg; ++j) {
            int s = ssrc[j0 + j];
            float cc = __expf(lrelu(a_src[s * 2 + h] + ad) - m) * inv;
            unsigned u0 = *(const unsigned*)(XLb + (size_t)s * 128 + c);
            acc0 += cc * __uint_as_float(u0 << 16);
            acc1 += cc * __uint_as_float(u0 & 0xffff0000u);
        }
    }
    float o0 = fmaxf(acc0 + bias[c], 0.f);
    float o1 = fmaxf(acc1 + bias[c + 1], 0.f);
    *(unsigned*)(out + (size_t)n * 128 + c) = (unsigned)f2bf(o0) | ((unsigned)f2bf(o1) << 16);
}

// ---------------- pooling (LDS-staged) + FC ----------------
#define PB 128
__global__ __launch_bounds__(128) void pool_kernel(const unsigned short* __restrict__ Hb,
                                                   const int* __restrict__ batch,
                                                   float* __restrict__ pooled, int* __restrict__ counts, int N) {
    __shared__ unsigned short Hs[PB * 128];
    __shared__ int bs[PB];
    int t = threadIdx.x;
    int base = blockIdx.x * PB;
    int lim = min(PB, N - base);
#pragma unroll
    for (int i = 0; i < 16; ++i) {
        int slot = i * 128 + t;
        int r = slot >> 4;
        int c8 = (slot & 15) << 3;
        uint4 u = make_uint4(0, 0, 0, 0);
        int n0 = base + r;
        if (n0 < N) u = *(const uint4*)(Hb + (size_t)n0 * 128 + c8);
        *(uint4*)(&Hs[r * 128 + c8]) = u;
    }
    if (t < lim) bs[t] = batch[base + t];
    __syncthreads();
    float acc = 0.f;
    int cur = bs[0];
    int runstart = 0;
    for (int i = 0; i < lim; ++i) {
        int g = bs[i];
        if (g != cur) {
            atomicAdd(&pooled[cur * 128 + t], acc);
            if (t == 0) atomicAdd(&counts[cur], i - runstart);
            cur = g;
            acc = 0.f;
            runstart = i;
        }
        acc += bf2f(Hs[i * 128 + t]);
    }
    atomicAdd(&pooled[cur * 128 + t], acc);
    if (t == 0) atomicAdd(&counts[cur], lim - runstart);
}

__global__ void final_kernel(const float* __restrict__ pooled, const int* __restrict__ counts,
                             const float* __restrict__ fc_w, const float* __restrict__ fc_b,
                             float* __restrict__ out) {
    int idx = blockIdx.x * 256 + threadIdx.x;
    if (idx >= 64 * 32) return;
    int g = idx >> 5, k = idx & 31;
    float invc = 1.f / fmaxf((float)counts[g], 1.f);
    float s = 0.f;
#pragma unroll 4
    for (int c = 0; c < 128; ++c) s += pooled[g * 128 + c] * fc_w[k * 128 + c];
    out[idx] = s * invc + fc_b[k];
}

// ---------------- host ----------------
extern "C" void kernel_launch(void* const* d_in, const int* in_sizes, int n_in,
                              void* d_out, int out_size, void* d_ws, size_t ws_size,
                              hipStream_t stream) {
    const float* x = (const float*)d_in[0];
    const int* ei = (const int*)d_in[1];
    const int* batch = (const int*)d_in[2];
    const float* W1 = (const float*)d_in[3];
    const float* as1 = (const float*)d_in[4];
    const float* ad1 = (const float*)d_in[5];
    const float* b1 = (const float*)d_in[6];
    const float* W2 = (const float*)d_in[7];
    const float* as2 = (const float*)d_in[8];
    const float* ad2 = (const float*)d_in[9];
    const float* b2 = (const float*)d_in[10];
    const float* fcw = (const float*)d_in[11];
    const float* fcb = (const float*)d_in[12];
    float* out = (float*)d_out;

    const int N = in_sizes[0] / 128;  // 50000
    const int E = in_sizes[1] / 2;    // 800000
    const int EN = E + N;

    char* p = (char*)d_ws;
    auto alloc = [&](size_t bytes) -> char* {
        char* r = p;
        p += (bytes + 255) & ~(size_t)255;
        return r;
    };
    unsigned short* XLb = (unsigned short*)alloc((size_t)N * 128 * 2);
    unsigned short* Hb = (unsigned short*)alloc((size_t)N * 128 * 2);
    float* a_src = (float*)alloc((size_t)N * 2 * 4);
    float* a_dst = (float*)alloc((size_t)N * 2 * 4);
    int* deg = (int*)alloc((size_t)N * 4);
    int* offs = (int*)alloc((size_t)(N + 1) * 4);
    int* cursor = (int*)alloc((size_t)N * 4);
    int* ssrc = (int*)alloc((size_t)EN * 4);
    float* Wt = (float*)alloc(16384 * 4);
    float* pooled = (float*)alloc(8192 * 4);
    int* counts = (int*)alloc(64 * 4);

    const int TB = 256;
    int gN = (N + TB - 1) / TB;
    int gE = (E + TB - 1) / TB;
    int gGemm = (N + GBM - 1) / GBM;
    int gWave = (N + 3) / 4;

    // CSR build (shared by both layers)
    hipMemsetAsync(deg, 0, (size_t)N * 4, stream);
    csr_hist<<<gE, TB, 0, stream>>>(ei, deg, E);
    scan_kernel<<<1, 1024, 0, stream>>>(deg, offs, N);
    csr_self_place<<<gN, TB, 0, stream>>>(offs, ssrc, cursor, N);
    csr_scatter<<<gE, TB, 0, stream>>>(ei, cursor, ssrc, E);

    // ---- layer 1 ----
    transpose_w<<<64, TB, 0, stream>>>(W1, Wt);
    gemm_kernel<float><<<gGemm, TB, 0, stream>>>(x, Wt, XLb, N);
    att_kernel<<<gWave, TB, 0, stream>>>(XLb, as1, ad1, a_src, a_dst, N);
    gat_node_kernel<<<gWave, TB, 0, stream>>>(XLb, a_src, a_dst, offs, ssrc, b1, Hb, N);

    // ---- layer 2 ----
    transpose_w<<<64, TB, 0, stream>>>(W2, Wt);
    gemm_kernel<unsigned short><<<gGemm, TB, 0, stream>>>(Hb, Wt, XLb, N);
    att_kernel<<<gWave, TB, 0, stream>>>(XLb, as2, ad2, a_src, a_dst, N);
    gat_node_kernel<<<gWave, TB, 0, stream>>>(XLb, a_src, a_dst, offs, ssrc, b2, Hb, N);

    // ---- pool + FC ----
    hipMemsetAsync(pooled, 0, 8192 * 4 + 256, stream);
    pool_kernel<<<(N + PB - 1) / PB, 128, 0, stream>>>(Hb, batch, pooled, counts, N);
    final_kernel<<<8, TB, 0, stream>>>(pooled, counts, fcw, fcb, out);
}

// Round 5
// 381.315 us; speedup vs baseline: 5.5546x; 1.2405x over previous
//
#include <hip/hip_runtime.h>
#include <hip/hip_bf16.h>

// SmallGAT R5: hierarchical coalesced scan (+fused self_place), att-dots fused into GEMM
// epilogue, merged transposes. bf16 activations, fp32 weights/softmax/accum.

#define NEG_SLOPE 0.2f

__device__ __forceinline__ float lrelu(float x) { return x > 0.f ? x : NEG_SLOPE * x; }
__device__ __forceinline__ float bf2f(unsigned short u) { return __uint_as_float(((unsigned)u) << 16); }
__device__ __forceinline__ unsigned short f2bf(float f) {
    unsigned x = __float_as_uint(f);
    return (unsigned short)((x + 0x7fffu + ((x >> 16) & 1u)) >> 16);  // RNE
}

// ---------------- CSR build ----------------
__global__ void csr_hist(const int* __restrict__ ei, int* __restrict__ deg, int E) {
    int e = blockIdx.x * 256 + threadIdx.x;
    if (e < E) atomicAdd(&deg[ei[E + e]], 1);
}

// hierarchical scan of (deg[n]+1). SCHUNK=4096 -> B = ceil(N/4096) blocks (<=64 for N<=262144).
#define SCHUNK 4096
__global__ __launch_bounds__(1024) void scan_partial(const int* __restrict__ deg, int* __restrict__ bsum, int N) {
    __shared__ int ws[16];
    int t = threadIdx.x;
    int n0 = blockIdx.x * SCHUNK + t * 4;
    int s = 0;
    if (n0 + 3 < N) {
        int4 v = *(const int4*)(deg + n0);
        s = v.x + v.y + v.z + v.w + 4;
    } else {
#pragma unroll
        for (int i = 0; i < 4; ++i) {
            int n = n0 + i;
            if (n < N) s += deg[n] + 1;
        }
    }
#pragma unroll
    for (int off = 32; off > 0; off >>= 1) s += __shfl_xor(s, off);
    if ((t & 63) == 0) ws[t >> 6] = s;
    __syncthreads();
    if (t == 0) {
        int tot = 0;
#pragma unroll
        for (int i = 0; i < 16; ++i) tot += ws[i];
        bsum[blockIdx.x] = tot;
    }
}

// single wave: exclusive-scan bsum[0..B), write total to offs[N]
__global__ __launch_bounds__(64) void scan_bsum(int* __restrict__ bsum, int* __restrict__ offs, int B, int N) {
    int t = threadIdx.x;
    int orig = (t < B) ? bsum[t] : 0;
    int v = orig;
#pragma unroll
    for (int off = 1; off < 64; off <<= 1) {
        int u = __shfl_up(v, off);
        if (t >= off) v += u;
    }
    if (t < B) bsum[t] = v - orig;          // exclusive prefix
    if (t == B - 1) offs[N] = v;            // grand total
}

// final: per-block LDS scan, write offs + self-loop placement + cursor
__global__ __launch_bounds__(1024) void scan_final(const int* __restrict__ deg, const int* __restrict__ bsum,
                                                   int* __restrict__ offs, int* __restrict__ ssrc,
                                                   int* __restrict__ cursor, int N) {
    __shared__ int sums[1024];
    int t = threadIdx.x;
    int n0 = blockIdx.x * SCHUNK + t * 4;
    int d0 = 0, d1 = 0, d2 = 0, d3 = 0;
    if (n0 + 3 < N) {
        int4 v = *(const int4*)(deg + n0);
        d0 = v.x + 1; d1 = v.y + 1; d2 = v.z + 1; d3 = v.w + 1;
    } else {
        if (n0 + 0 < N) d0 = deg[n0 + 0] + 1;
        if (n0 + 1 < N) d1 = deg[n0 + 1] + 1;
        if (n0 + 2 < N) d2 = deg[n0 + 2] + 1;
        if (n0 + 3 < N) d3 = deg[n0 + 3] + 1;
    }
    int tot = d0 + d1 + d2 + d3;
    sums[t] = tot;
    __syncthreads();
    for (int off = 1; off < 1024; off <<= 1) {
        int x = (t >= off) ? sums[t - off] : 0;
        __syncthreads();
        sums[t] += x;
        __syncthreads();
    }
    int run = bsum[blockIdx.x] + sums[t] - tot;
    int dd[4] = {d0, d1, d2, d3};
#pragma unroll
    for (int i = 0; i < 4; ++i) {
        int n = n0 + i;
        if (dd[i] > 0) {
            offs[n] = run;
            ssrc[run] = n;        // self-loop at slot 0
            cursor[n] = run + 1;
            run += dd[i];
        }
    }
}

__global__ void csr_scatter(const int* __restrict__ ei, int* __restrict__ cursor,
                            int* __restrict__ ssrc, int E) {
    int e = blockIdx.x * 256 + threadIdx.x;
    if (e >= E) return;
    int d = ei[E + e];
    int pos = atomicAdd(&cursor[d], 1);
    ssrc[pos] = ei[e];
}

// ---------------- dense: both W transposes in one launch ----------------
__global__ void transpose_w2(const float* __restrict__ W1, const float* __restrict__ W2,
                             float* __restrict__ Wt1, float* __restrict__ Wt2) {
    int i = blockIdx.x * 256 + threadIdx.x;
    if (i < 16384) {
        int n = i & 127, k = i >> 7;
        Wt1[i] = W1[n * 128 + k];
    } else if (i < 32768) {
        int j = i - 16384;
        int n = j & 127, k = j >> 7;
        Wt2[j] = W2[n * 128 + k];
    }
}

#define GBM 32
// out[m][n] = sum_k A[m][k] * Wt[k][n]; fused a_src/a_dst epilogue
template <typename T>
__global__ __launch_bounds__(256) void gemm_kernel(const T* __restrict__ A, const float* __restrict__ Wt,
                                                   unsigned short* __restrict__ out,
                                                   const float* __restrict__ att_s, const float* __restrict__ att_d,
                                                   float* __restrict__ a_src, float* __restrict__ a_dst, int M) {
    __shared__ float Ws[128 * 128];   // [k][n] 64KB
    __shared__ float As[GBM][128];    // 16KB
    int tid = threadIdx.x;
    int m0 = blockIdx.x * GBM;
    const float4* Wt4 = (const float4*)Wt;
    float4* Ws4 = (float4*)Ws;
#pragma unroll
    for (int i = 0; i < 16; ++i) Ws4[tid + i * 256] = Wt4[tid + i * 256];
    if constexpr (sizeof(T) == 4) {
#pragma unroll
        for (int i = 0; i < 4; ++i) {
            int j = tid + i * 256;
            int r = j >> 5;
            int c4 = (j & 31) << 2;
            int m = m0 + r;
            float4 v = make_float4(0.f, 0.f, 0.f, 0.f);
            if (m < M) v = *(const float4*)((const float*)A + (size_t)m * 128 + c4);
            *(float4*)(&As[r][c4]) = v;
        }
    } else {
#pragma unroll
        for (int i = 0; i < 2; ++i) {
            int j = tid + i * 256;
            int r = j >> 4;
            int c8 = (j & 15) << 3;
            int m = m0 + r;
            uint4 u = make_uint4(0, 0, 0, 0);
            if (m < M) u = *(const uint4*)((const unsigned short*)A + (size_t)m * 128 + c8);
            float* dst = &As[r][c8];
            dst[0] = __uint_as_float(u.x << 16); dst[1] = __uint_as_float(u.x & 0xffff0000u);
            dst[2] = __uint_as_float(u.y << 16); dst[3] = __uint_as_float(u.y & 0xffff0000u);
            dst[4] = __uint_as_float(u.z << 16); dst[5] = __uint_as_float(u.z & 0xffff0000u);
            dst[6] = __uint_as_float(u.w << 16); dst[7] = __uint_as_float(u.w & 0xffff0000u);
        }
    }
    __syncthreads();
    int rg = tid >> 5;  // rows rg*4..rg*4+3
    int ct = tid & 31;  // cols ct*4..ct*4+3
    float acc[4][4] = {{0.f}};
#pragma unroll 4
    for (int k = 0; k < 128; ++k) {
        float4 b = *(const float4*)(&Ws[k * 128 + ct * 4]);
        float a0 = As[rg * 4 + 0][k];
        float a1 = As[rg * 4 + 1][k];
        float a2 = As[rg * 4 + 2][k];
        float a3 = As[rg * 4 + 3][k];
        acc[0][0] += a0 * b.x; acc[0][1] += a0 * b.y; acc[0][2] += a0 * b.z; acc[0][3] += a0 * b.w;
        acc[1][0] += a1 * b.x; acc[1][1] += a1 * b.y; acc[1][2] += a1 * b.z; acc[1][3] += a1 * b.w;
        acc[2][0] += a2 * b.x; acc[2][1] += a2 * b.y; acc[2][2] += a2 * b.z; acc[2][3] += a2 * b.w;
        acc[3][0] += a3 * b.x; acc[3][1] += a3 * b.y; acc[3][2] += a3 * b.z; acc[3][3] += a3 * b.w;
    }
    // store bf16
#pragma unroll
    for (int i = 0; i < 4; ++i) {
        int m = m0 + rg * 4 + i;
        if (m < M) {
            unsigned lo = (unsigned)f2bf(acc[i][0]) | ((unsigned)f2bf(acc[i][1]) << 16);
            unsigned hi = (unsigned)f2bf(acc[i][2]) | ((unsigned)f2bf(acc[i][3]) << 16);
            *(uint2*)(out + (size_t)m * 128 + ct * 4) = make_uint2(lo, hi);
        }
    }
    // fused attention dots: 16-lane group (same rg, same head) holds the head's 64 chans
    float4 asv = *(const float4*)(att_s + ct * 4);
    float4 adv = *(const float4*)(att_d + ct * 4);
#pragma unroll
    for (int i = 0; i < 4; ++i) {
        float ps = acc[i][0] * asv.x + acc[i][1] * asv.y + acc[i][2] * asv.z + acc[i][3] * asv.w;
        float pd = acc[i][0] * adv.x + acc[i][1] * adv.y + acc[i][2] * adv.z + acc[i][3] * adv.w;
#pragma unroll
        for (int off = 1; off < 16; off <<= 1) {
            ps += __shfl_xor(ps, off);
            pd += __shfl_xor(pd, off);
        }
        if ((ct & 15) == 0) {
            int m = m0 + rg * 4 + i;
            if (m < M) {
                int h = ct >> 4;
                a_src[m * 2 + h] = ps;
                a_dst[m * 2 + h] = pd;
            }
        }
    }
}

// ---------------- fused per-node softmax + aggregate (wave per node) ----------------
#define MAXD 128
__global__ __launch_bounds__(256) void gat_node_kernel(const unsigned short* __restrict__ XLb,
                                                       const float* __restrict__ a_src, const float* __restrict__ a_dst,
                                                       const int* __restrict__ offs, const int* __restrict__ ssrc,
                                                       const float* __restrict__ bias,
                                                       unsigned short* __restrict__ out, int N) {
    __shared__ float coeff[4][2][MAXD];
    __shared__ int srcs[4][MAXD];
    int t = threadIdx.x;
    int w = t >> 6, l = t & 63;
    int n = blockIdx.x * 4 + w;
    if (n >= N) return;
    int h = l >> 5, sl = l & 31;
    int c = 2 * l;
    int j0 = offs[n], j1 = offs[n + 1];
    int deg = j1 - j0;
    float ad = a_dst[n * 2 + h];
    float acc0 = 0.f, acc1 = 0.f;
    if (deg <= MAXD) {
        float m = -1e30f;
        for (int k = sl; k < deg; k += 32) {
            int s = ssrc[j0 + k];
            if (h == 0) srcs[w][k] = s;
            float al = lrelu(a_src[s * 2 + h] + ad);
            coeff[w][h][k] = al;
            m = fmaxf(m, al);
        }
#pragma unroll
        for (int off = 16; off > 0; off >>= 1) m = fmaxf(m, __shfl_xor(m, off));
        float sum = 0.f;
        for (int k = sl; k < deg; k += 32) {
            float e = __expf(coeff[w][h][k] - m);
            coeff[w][h][k] = e;
            sum += e;
        }
#pragma unroll
        for (int off = 16; off > 0; off >>= 1) sum += __shfl_xor(sum, off);
        float inv = 1.f / fmaxf(sum, 1e-16f);
        int j = 0;
        for (; j + 1 < deg; j += 2) {
            float c0 = coeff[w][h][j] * inv;
            float c1 = coeff[w][h][j + 1] * inv;
            int s0 = srcs[w][j];
            int s1 = srcs[w][j + 1];
            unsigned u0 = *(const unsigned*)(XLb + (size_t)s0 * 128 + c);
            unsigned u1 = *(const unsigned*)(XLb + (size_t)s1 * 128 + c);
            acc0 += c0 * __uint_as_float(u0 << 16) + c1 * __uint_as_float(u1 << 16);
            acc1 += c0 * __uint_as_float(u0 & 0xffff0000u) + c1 * __uint_as_float(u1 & 0xffff0000u);
        }
        if (j < deg) {
            float c0 = coeff[w][h][j] * inv;
            int s0 = srcs[w][j];
            unsigned u0 = *(const unsigned*)(XLb + (size_t)s0 * 128 + c);
            acc0 += c0 * __uint_as_float(u0 << 16);
            acc1 += c0 * __uint_as_float(u0 & 0xffff0000u);
        }
    } else {
        // streaming fallback (recompute), deg > MAXD
        float m = -1e30f;
        for (int k = sl; k < deg; k += 32) {
            int s = ssrc[j0 + k];
            m = fmaxf(m, lrelu(a_src[s * 2 + h] + ad));
        }
#pragma unroll
        for (int off = 16; off > 0; off >>= 1) m = fmaxf(m, __shfl_xor(m, off));
        float sum = 0.f;
        for (int k = sl; k < deg; k += 32) {
            int s = ssrc[j0 + k];
            sum += __expf(lrelu(a_src[s * 2 + h] + ad) - m);
        }
#pragma unroll
        for (int off = 16; off > 0; off >>= 1) sum += __shfl_xor(sum, off);
        float inv = 1.f / fmaxf(sum, 1e-16f);
        for (int j = 0; j < deg; ++j) {
            int s = ssrc[j0 + j];
            float cc = __expf(lrelu(a_src[s * 2 + h] + ad) - m) * inv;
            unsigned u0 = *(const unsigned*)(XLb + (size_t)s * 128 + c);
            acc0 += cc * __uint_as_float(u0 << 16);
            acc1 += cc * __uint_as_float(u0 & 0xffff0000u);
        }
    }
    float o0 = fmaxf(acc0 + bias[c], 0.f);
    float o1 = fmaxf(acc1 + bias[c + 1], 0.f);
    *(unsigned*)(out + (size_t)n * 128 + c) = (unsigned)f2bf(o0) | ((unsigned)f2bf(o1) << 16);
}

// ---------------- pooling (LDS-staged) + FC ----------------
#define PB 128
__global__ __launch_bounds__(128) void pool_kernel(const unsigned short* __restrict__ Hb,
                                                   const int* __restrict__ batch,
                                                   float* __restrict__ pooled, int* __restrict__ counts, int N) {
    __shared__ unsigned short Hs[PB * 128];
    __shared__ int bs[PB];
    int t = threadIdx.x;
    int base = blockIdx.x * PB;
    int lim = min(PB, N - base);
#pragma unroll
    for (int i = 0; i < 16; ++i) {
        int slot = i * 128 + t;
        int r = slot >> 4;
        int c8 = (slot & 15) << 3;
        uint4 u = make_uint4(0, 0, 0, 0);
        int n0 = base + r;
        if (n0 < N) u = *(const uint4*)(Hb + (size_t)n0 * 128 + c8);
        *(uint4*)(&Hs[r * 128 + c8]) = u;
    }
    if (t < lim) bs[t] = batch[base + t];
    __syncthreads();
    float acc = 0.f;
    int cur = bs[0];
    int runstart = 0;
    for (int i = 0; i < lim; ++i) {
        int g = bs[i];
        if (g != cur) {
            atomicAdd(&pooled[cur * 128 + t], acc);
            if (t == 0) atomicAdd(&counts[cur], i - runstart);
            cur = g;
            acc = 0.f;
            runstart = i;
        }
        acc += bf2f(Hs[i * 128 + t]);
    }
    atomicAdd(&pooled[cur * 128 + t], acc);
    if (t == 0) atomicAdd(&counts[cur], lim - runstart);
}

__global__ void final_kernel(const float* __restrict__ pooled, const int* __restrict__ counts,
                             const float* __restrict__ fc_w, const float* __restrict__ fc_b,
                             float* __restrict__ out) {
    int idx = blockIdx.x * 256 + threadIdx.x;
    if (idx >= 64 * 32) return;
    int g = idx >> 5, k = idx & 31;
    float invc = 1.f / fmaxf((float)counts[g], 1.f);
    float s = 0.f;
#pragma unroll 4
    for (int c = 0; c < 128; ++c) s += pooled[g * 128 + c] * fc_w[k * 128 + c];
    out[idx] = s * invc + fc_b[k];
}

// ---------------- host ----------------
extern "C" void kernel_launch(void* const* d_in, const int* in_sizes, int n_in,
                              void* d_out, int out_size, void* d_ws, size_t ws_size,
                              hipStream_t stream) {
    const float* x = (const float*)d_in[0];
    const int* ei = (const int*)d_in[1];
    const int* batch = (const int*)d_in[2];
    const float* W1 = (const float*)d_in[3];
    const float* as1 = (const float*)d_in[4];
    const float* ad1 = (const float*)d_in[5];
    const float* b1 = (const float*)d_in[6];
    const float* W2 = (const float*)d_in[7];
    const float* as2 = (const float*)d_in[8];
    const float* ad2 = (const float*)d_in[9];
    const float* b2 = (const float*)d_in[10];
    const float* fcw = (const float*)d_in[11];
    const float* fcb = (const float*)d_in[12];
    float* out = (float*)d_out;

    const int N = in_sizes[0] / 128;  // 50000
    const int E = in_sizes[1] / 2;    // 800000
    const int EN = E + N;

    char* p = (char*)d_ws;
    auto alloc = [&](size_t bytes) -> char* {
        char* r = p;
        p += (bytes + 255) & ~(size_t)255;
        return r;
    };
    unsigned short* XLb = (unsigned short*)alloc((size_t)N * 128 * 2);
    unsigned short* Hb = (unsigned short*)alloc((size_t)N * 128 * 2);
    float* a_src = (float*)alloc((size_t)N * 2 * 4);
    float* a_dst = (float*)alloc((size_t)N * 2 * 4);
    int* deg = (int*)alloc((size_t)N * 4);
    int* offs = (int*)alloc((size_t)(N + 1) * 4);
    int* cursor = (int*)alloc((size_t)N * 4);
    int* ssrc = (int*)alloc((size_t)EN * 4);
    int* bsum = (int*)alloc(64 * 4);
    float* Wt1 = (float*)alloc(16384 * 4);
    float* Wt2 = (float*)alloc(16384 * 4);
    float* pooled = (float*)alloc(8192 * 4);
    int* counts = (int*)alloc(64 * 4);

    const int TB = 256;
    int gE = (E + TB - 1) / TB;
    int gGemm = (N + GBM - 1) / GBM;
    int gWave = (N + 3) / 4;
    int B = (N + SCHUNK - 1) / SCHUNK;  // <=64 for N<=262144

    // CSR build (shared by both layers)
    hipMemsetAsync(deg, 0, (size_t)N * 4, stream);
    transpose_w2<<<128, TB, 0, stream>>>(W1, W2, Wt1, Wt2);
    csr_hist<<<gE, TB, 0, stream>>>(ei, deg, E);
    scan_partial<<<B, 1024, 0, stream>>>(deg, bsum, N);
    scan_bsum<<<1, 64, 0, stream>>>(bsum, offs, B, N);
    scan_final<<<B, 1024, 0, stream>>>(deg, bsum, offs, ssrc, cursor, N);
    csr_scatter<<<gE, TB, 0, stream>>>(ei, cursor, ssrc, E);

    // ---- layer 1 ----
    gemm_kernel<float><<<gGemm, TB, 0, stream>>>(x, Wt1, XLb, as1, ad1, a_src, a_dst, N);
    gat_node_kernel<<<gWave, TB, 0, stream>>>(XLb, a_src, a_dst, offs, ssrc, b1, Hb, N);

    // ---- layer 2 ----
    gemm_kernel<unsigned short><<<gGemm, TB, 0, stream>>>(Hb, Wt2, XLb, as2, ad2, a_src, a_dst, N);
    gat_node_kernel<<<gWave, TB, 0, stream>>>(XLb, a_src, a_dst, offs, ssrc, b2, Hb, N);

    // ---- pool + FC ----
    hipMemsetAsync(pooled, 0, 8192 * 4 + 256, stream);
    pool_kernel<<<(N + PB - 1) / PB, 128, 0, stream>>>(Hb, batch, pooled, counts, N);
    final_kernel<<<8, TB, 0, stream>>>(pooled, counts, fcw, fcb, out);
}

// Round 6
// 322.383 us; speedup vs baseline: 6.5699x; 1.1828x over previous
//
#include <hip/hip_runtime.h>
#include <hip/hip_bf16.h>

// SmallGAT R6: bucket-based CSR build (XCD-local writes, no random global scatter).
// bf16 activations, fp32 weights/softmax/accum; att-dots fused into GEMM epilogue.
// Assumes N <= 65536 (bucket = dst>>8 fits 256 buckets; N=50000 here).

#define NEG_SLOPE 0.2f

__device__ __forceinline__ float lrelu(float x) { return x > 0.f ? x : NEG_SLOPE * x; }
__device__ __forceinline__ float bf2f(unsigned short u) { return __uint_as_float(((unsigned)u) << 16); }
__device__ __forceinline__ unsigned short f2bf(float f) {
    unsigned x = __float_as_uint(f);
    return (unsigned short)((x + 0x7fffu + ((x >> 16) & 1u)) >> 16);  // RNE
}

// ---------------- CSR build via dst-range buckets ----------------
// bucket b = dst >> 8 ; NB = ceil(N/256) buckets.

// per-block LDS hist -> global bucket counts
__global__ __launch_bounds__(256) void bucket_hist(const int* __restrict__ ei, int* __restrict__ bcount, int E) {
    __shared__ int hist[256];
    int t = threadIdx.x;
    hist[t] = 0;
    __syncthreads();
    int eb = blockIdx.x * 4096;
#pragma unroll
    for (int i = 0; i < 16; ++i) {
        int e = eb + i * 256 + t;
        if (e < E) atomicAdd(&hist[ei[E + e] >> 8], 1);
    }
    __syncthreads();
    if (hist[t]) atomicAdd(&bcount[t], hist[t]);
}

// one block: exclusive scan bucket counts -> ebase[0..NB], cursors, offs[N]
__global__ __launch_bounds__(256) void bucket_scan(const int* __restrict__ bcount, int* __restrict__ ebase,
                                                   int* __restrict__ bcur, int* __restrict__ offs, int NB, int N, int E) {
    __shared__ int sc[256];
    int t = threadIdx.x;
    int cnt = (t < NB) ? bcount[t] : 0;
    sc[t] = cnt;
    __syncthreads();
    for (int off = 1; off < 256; off <<= 1) {
        int x = (t >= off) ? sc[t - off] : 0;
        __syncthreads();
        sc[t] += x;
        __syncthreads();
    }
    int excl = sc[t] - cnt;
    if (t < NB) {
        ebase[t] = excl;
        bcur[t] = excl;
    }
    if (t == NB - 1) ebase[NB] = sc[t];
    if (t == 0) offs[N] = E + N;
}

// stable-enough bucket sort: per-block chunk reservation + packed write (src<<8 | dst&255)
__global__ __launch_bounds__(1024) void bucket_scatter(const int* __restrict__ ei, int* __restrict__ bcur,
                                                       unsigned* __restrict__ pk, int E) {
    __shared__ int hist[256];
    __shared__ int base[256];
    int t = threadIdx.x;
    if (t < 256) hist[t] = 0;
    __syncthreads();
    int eb = blockIdx.x * 16384;
    int d[16];
#pragma unroll
    for (int i = 0; i < 16; ++i) {
        int e = eb + i * 1024 + t;
        if (e < E) {
            d[i] = ei[E + e];
            atomicAdd(&hist[d[i] >> 8], 1);
        } else {
            d[i] = -1;
        }
    }
    __syncthreads();
    if (t < 256) {
        int c = hist[t];
        base[t] = c ? atomicAdd(&bcur[t], c) : 0;
        hist[t] = 0;
    }
    __syncthreads();
#pragma unroll
    for (int i = 0; i < 16; ++i) {
        if (d[i] >= 0) {
            int s = ei[eb + i * 1024 + t];
            int bk = d[i] >> 8;
            int r = atomicAdd(&hist[bk], 1);
            pk[base[bk] + r] = ((unsigned)s << 8) | (unsigned)(d[i] & 255);
        }
    }
}

// block = bucket: LDS degree hist -> scan -> offs/self-loops/edges, all in one 17KB window
__global__ __launch_bounds__(256) void csr_build(const unsigned* __restrict__ pk, const int* __restrict__ ebase,
                                                 int* __restrict__ offs, int* __restrict__ ssrc, int N) {
    __shared__ int deg[256];
    __shared__ int curs[256];
    __shared__ int sc[256];
    int t = threadIdx.x;
    int b = blockIdx.x;
    deg[t] = 0;
    __syncthreads();
    int e0 = ebase[b], e1 = ebase[b + 1];
    for (int j = e0 + t; j < e1; j += 256) atomicAdd(&deg[pk[j] & 255], 1);
    __syncthreads();
    int nb0 = b * 256;
    int ncount = min(256, N - nb0);
    int v = (t < ncount) ? deg[t] + 1 : 0;
    sc[t] = v;
    __syncthreads();
    for (int off = 1; off < 256; off <<= 1) {
        int x = (t >= off) ? sc[t - off] : 0;
        __syncthreads();
        sc[t] += x;
        __syncthreads();
    }
    int nbase = e0 + b * 256;  // edges before bucket + self-loops before bucket
    if (t < ncount) {
        int o = nbase + sc[t] - v;
        offs[nb0 + t] = o;
        ssrc[o] = nb0 + t;   // self-loop first
        curs[t] = o + 1;
    }
    __syncthreads();
    for (int j = e0 + t; j < e1; j += 256) {
        unsigned e = pk[j];
        int pos = atomicAdd(&curs[e & 255], 1);
        ssrc[pos] = (int)(e >> 8);
    }
}

// ---------------- dense: both W transposes in one launch ----------------
__global__ void transpose_w2(const float* __restrict__ W1, const float* __restrict__ W2,
                             float* __restrict__ Wt1, float* __restrict__ Wt2) {
    int i = blockIdx.x * 256 + threadIdx.x;
    if (i < 16384) {
        int n = i & 127, k = i >> 7;
        Wt1[i] = W1[n * 128 + k];
    } else if (i < 32768) {
        int j = i - 16384;
        int n = j & 127, k = j >> 7;
        Wt2[j] = W2[n * 128 + k];
    }
}

#define GBM 32
// out[m][n] = sum_k A[m][k] * Wt[k][n]; fused a_src/a_dst epilogue
template <typename T>
__global__ __launch_bounds__(256) void gemm_kernel(const T* __restrict__ A, const float* __restrict__ Wt,
                                                   unsigned short* __restrict__ out,
                                                   const float* __restrict__ att_s, const float* __restrict__ att_d,
                                                   float* __restrict__ a_src, float* __restrict__ a_dst, int M) {
    __shared__ float Ws[128 * 128];   // [k][n] 64KB
    __shared__ float As[GBM][128];    // 16KB
    int tid = threadIdx.x;
    int m0 = blockIdx.x * GBM;
    const float4* Wt4 = (const float4*)Wt;
    float4* Ws4 = (float4*)Ws;
#pragma unroll
    for (int i = 0; i < 16; ++i) Ws4[tid + i * 256] = Wt4[tid + i * 256];
    if constexpr (sizeof(T) == 4) {
#pragma unroll
        for (int i = 0; i < 4; ++i) {
            int j = tid + i * 256;
            int r = j >> 5;
            int c4 = (j & 31) << 2;
            int m = m0 + r;
            float4 v = make_float4(0.f, 0.f, 0.f, 0.f);
            if (m < M) v = *(const float4*)((const float*)A + (size_t)m * 128 + c4);
            *(float4*)(&As[r][c4]) = v;
        }
    } else {
#pragma unroll
        for (int i = 0; i < 2; ++i) {
            int j = tid + i * 256;
            int r = j >> 4;
            int c8 = (j & 15) << 3;
            int m = m0 + r;
            uint4 u = make_uint4(0, 0, 0, 0);
            if (m < M) u = *(const uint4*)((const unsigned short*)A + (size_t)m * 128 + c8);
            float* dst = &As[r][c8];
            dst[0] = __uint_as_float(u.x << 16); dst[1] = __uint_as_float(u.x & 0xffff0000u);
            dst[2] = __uint_as_float(u.y << 16); dst[3] = __uint_as_float(u.y & 0xffff0000u);
            dst[4] = __uint_as_float(u.z << 16); dst[5] = __uint_as_float(u.z & 0xffff0000u);
            dst[6] = __uint_as_float(u.w << 16); dst[7] = __uint_as_float(u.w & 0xffff0000u);
        }
    }
    __syncthreads();
    int rg = tid >> 5;  // rows rg*4..rg*4+3
    int ct = tid & 31;  // cols ct*4..ct*4+3
    float acc[4][4] = {{0.f}};
#pragma unroll 4
    for (int k = 0; k < 128; ++k) {
        float4 b = *(const float4*)(&Ws[k * 128 + ct * 4]);
        float a0 = As[rg * 4 + 0][k];
        float a1 = As[rg * 4 + 1][k];
        float a2 = As[rg * 4 + 2][k];
        float a3 = As[rg * 4 + 3][k];
        acc[0][0] += a0 * b.x; acc[0][1] += a0 * b.y; acc[0][2] += a0 * b.z; acc[0][3] += a0 * b.w;
        acc[1][0] += a1 * b.x; acc[1][1] += a1 * b.y; acc[1][2] += a1 * b.z; acc[1][3] += a1 * b.w;
        acc[2][0] += a2 * b.x; acc[2][1] += a2 * b.y; acc[2][2] += a2 * b.z; acc[2][3] += a2 * b.w;
        acc[3][0] += a3 * b.x; acc[3][1] += a3 * b.y; acc[3][2] += a3 * b.z; acc[3][3] += a3 * b.w;
    }
    // store bf16
#pragma unroll
    for (int i = 0; i < 4; ++i) {
        int m = m0 + rg * 4 + i;
        if (m < M) {
            unsigned lo = (unsigned)f2bf(acc[i][0]) | ((unsigned)f2bf(acc[i][1]) << 16);
            unsigned hi = (unsigned)f2bf(acc[i][2]) | ((unsigned)f2bf(acc[i][3]) << 16);
            *(uint2*)(out + (size_t)m * 128 + ct * 4) = make_uint2(lo, hi);
        }
    }
    // fused attention dots: 16-lane group (same rg, same head) holds the head's 64 chans
    float4 asv = *(const float4*)(att_s + ct * 4);
    float4 adv = *(const float4*)(att_d + ct * 4);
#pragma unroll
    for (int i = 0; i < 4; ++i) {
        float ps = acc[i][0] * asv.x + acc[i][1] * asv.y + acc[i][2] * asv.z + acc[i][3] * asv.w;
        float pd = acc[i][0] * adv.x + acc[i][1] * adv.y + acc[i][2] * adv.z + acc[i][3] * adv.w;
#pragma unroll
        for (int off = 1; off < 16; off <<= 1) {
            ps += __shfl_xor(ps, off);
            pd += __shfl_xor(pd, off);
        }
        if ((ct & 15) == 0) {
            int m = m0 + rg * 4 + i;
            if (m < M) {
                int h = ct >> 4;
                a_src[m * 2 + h] = ps;
                a_dst[m * 2 + h] = pd;
            }
        }
    }
}

// ---------------- fused per-node softmax + aggregate (wave per node) ----------------
#define MAXD 128
__global__ __launch_bounds__(256) void gat_node_kernel(const unsigned short* __restrict__ XLb,
                                                       const float* __restrict__ a_src, const float* __restrict__ a_dst,
                                                       const int* __restrict__ offs, const int* __restrict__ ssrc,
                                                       const float* __restrict__ bias,
                                                       unsigned short* __restrict__ out, int N) {
    __shared__ float coeff[4][2][MAXD];
    __shared__ int srcs[4][MAXD];
    int t = threadIdx.x;
    int w = t >> 6, l = t & 63;
    int n = blockIdx.x * 4 + w;
    if (n >= N) return;
    int h = l >> 5, sl = l & 31;
    int c = 2 * l;
    int j0 = offs[n], j1 = offs[n + 1];
    int deg = j1 - j0;
    float ad = a_dst[n * 2 + h];
    float acc0 = 0.f, acc1 = 0.f;
    if (deg <= MAXD) {
        float m = -1e30f;
        for (int k = sl; k < deg; k += 32) {
            int s = ssrc[j0 + k];
            if (h == 0) srcs[w][k] = s;
            float al = lrelu(a_src[s * 2 + h] + ad);
            coeff[w][h][k] = al;
            m = fmaxf(m, al);
        }
#pragma unroll
        for (int off = 16; off > 0; off >>= 1) m = fmaxf(m, __shfl_xor(m, off));
        float sum = 0.f;
        for (int k = sl; k < deg; k += 32) {
            float e = __expf(coeff[w][h][k] - m);
            coeff[w][h][k] = e;
            sum += e;
        }
#pragma unroll
        for (int off = 16; off > 0; off >>= 1) sum += __shfl_xor(sum, off);
        float inv = 1.f / fmaxf(sum, 1e-16f);
        int j = 0;
        for (; j + 1 < deg; j += 2) {
            float c0 = coeff[w][h][j] * inv;
            float c1 = coeff[w][h][j + 1] * inv;
            int s0 = srcs[w][j];
            int s1 = srcs[w][j + 1];
            unsigned u0 = *(const unsigned*)(XLb + (size_t)s0 * 128 + c);
            unsigned u1 = *(const unsigned*)(XLb + (size_t)s1 * 128 + c);
            acc0 += c0 * __uint_as_float(u0 << 16) + c1 * __uint_as_float(u1 << 16);
            acc1 += c0 * __uint_as_float(u0 & 0xffff0000u) + c1 * __uint_as_float(u1 & 0xffff0000u);
        }
        if (j < deg) {
            float c0 = coeff[w][h][j] * inv;
            int s0 = srcs[w][j];
            unsigned u0 = *(const unsigned*)(XLb + (size_t)s0 * 128 + c);
            acc0 += c0 * __uint_as_float(u0 << 16);
            acc1 += c0 * __uint_as_float(u0 & 0xffff0000u);
        }
    } else {
        // streaming fallback (recompute), deg > MAXD
        float m = -1e30f;
        for (int k = sl; k < deg; k += 32) {
            int s = ssrc[j0 + k];
            m = fmaxf(m, lrelu(a_src[s * 2 + h] + ad));
        }
#pragma unroll
        for (int off = 16; off > 0; off >>= 1) m = fmaxf(m, __shfl_xor(m, off));
        float sum = 0.f;
        for (int k = sl; k < deg; k += 32) {
            int s = ssrc[j0 + k];
            sum += __expf(lrelu(a_src[s * 2 + h] + ad) - m);
        }
#pragma unroll
        for (int off = 16; off > 0; off >>= 1) sum += __shfl_xor(sum, off);
        float inv = 1.f / fmaxf(sum, 1e-16f);
        for (int j = 0; j < deg; ++j) {
            int s = ssrc[j0 + j];
            float cc = __expf(lrelu(a_src[s * 2 + h] + ad) - m) * inv;
            unsigned u0 = *(const unsigned*)(XLb + (size_t)s * 128 + c);
            acc0 += cc * __uint_as_float(u0 << 16);
            acc1 += cc * __uint_as_float(u0 & 0xffff0000u);
        }
    }
    float o0 = fmaxf(acc0 + bias[c], 0.f);
    float o1 = fmaxf(acc1 + bias[c + 1], 0.f);
    *(unsigned*)(out + (size_t)n * 128 + c) = (unsigned)f2bf(o0) | ((unsigned)f2bf(o1) << 16);
}

// ---------------- pooling (LDS-staged) + FC ----------------
#define PB 128
__global__ __launch_bounds__(128) void pool_kernel(const unsigned short* __restrict__ Hb,
                                                   const int* __restrict__ batch,
                                                   float* __restrict__ pooled, int* __restrict__ counts, int N) {
    __shared__ unsigned short Hs[PB * 128];
    __shared__ int bs[PB];
    int t = threadIdx.x;
    int base = blockIdx.x * PB;
    int lim = min(PB, N - base);
#pragma unroll
    for (int i = 0; i < 16; ++i) {
        int slot = i * 128 + t;
        int r = slot >> 4;
        int c8 = (slot & 15) << 3;
        uint4 u = make_uint4(0, 0, 0, 0);
        int n0 = base + r;
        if (n0 < N) u = *(const uint4*)(Hb + (size_t)n0 * 128 + c8);
        *(uint4*)(&Hs[r * 128 + c8]) = u;
    }
    if (t < lim) bs[t] = batch[base + t];
    __syncthreads();
    float acc = 0.f;
    int cur = bs[0];
    int runstart = 0;
    for (int i = 0; i < lim; ++i) {
        int g = bs[i];
        if (g != cur) {
            atomicAdd(&pooled[cur * 128 + t], acc);
            if (t == 0) atomicAdd(&counts[cur], i - runstart);
            cur = g;
            acc = 0.f;
            runstart = i;
        }
        acc += bf2f(Hs[i * 128 + t]);
    }
    atomicAdd(&pooled[cur * 128 + t], acc);
    if (t == 0) atomicAdd(&counts[cur], lim - runstart);
}

__global__ void final_kernel(const float* __restrict__ pooled, const int* __restrict__ counts,
                             const float* __restrict__ fc_w, const float* __restrict__ fc_b,
                             float* __restrict__ out) {
    int idx = blockIdx.x * 256 + threadIdx.x;
    if (idx >= 64 * 32) return;
    int g = idx >> 5, k = idx & 31;
    float invc = 1.f / fmaxf((float)counts[g], 1.f);
    float s = 0.f;
#pragma unroll 4
    for (int c = 0; c < 128; ++c) s += pooled[g * 128 + c] * fc_w[k * 128 + c];
    out[idx] = s * invc + fc_b[k];
}

// ---------------- host ----------------
extern "C" void kernel_launch(void* const* d_in, const int* in_sizes, int n_in,
                              void* d_out, int out_size, void* d_ws, size_t ws_size,
                              hipStream_t stream) {
    const float* x = (const float*)d_in[0];
    const int* ei = (const int*)d_in[1];
    const int* batch = (const int*)d_in[2];
    const float* W1 = (const float*)d_in[3];
    const float* as1 = (const float*)d_in[4];
    const float* ad1 = (const float*)d_in[5];
    const float* b1 = (const float*)d_in[6];
    const float* W2 = (const float*)d_in[7];
    const float* as2 = (const float*)d_in[8];
    const float* ad2 = (const float*)d_in[9];
    const float* b2 = (const float*)d_in[10];
    const float* fcw = (const float*)d_in[11];
    const float* fcb = (const float*)d_in[12];
    float* out = (float*)d_out;

    const int N = in_sizes[0] / 128;  // 50000
    const int E = in_sizes[1] / 2;    // 800000
    const int EN = E + N;
    const int NB = (N + 255) >> 8;    // 196 buckets

    char* p = (char*)d_ws;
    auto alloc = [&](size_t bytes) -> char* {
        char* r = p;
        p += (bytes + 255) & ~(size_t)255;
        return r;
    };
    unsigned short* XLb = (unsigned short*)alloc((size_t)N * 128 * 2);
    unsigned short* Hb = (unsigned short*)alloc((size_t)N * 128 * 2);
    float* a_src = (float*)alloc((size_t)N * 2 * 4);
    float* a_dst = (float*)alloc((size_t)N * 2 * 4);
    int* offs = (int*)alloc((size_t)(N + 1) * 4);
    int* ssrc = (int*)alloc((size_t)EN * 4);
    unsigned* pk = (unsigned*)alloc((size_t)E * 4);
    int* ebase = (int*)alloc((size_t)(NB + 1) * 4);
    int* bcur = (int*)alloc((size_t)NB * 4);
    float* Wt1 = (float*)alloc(16384 * 4);
    float* Wt2 = (float*)alloc(16384 * 4);
    // zeroed region: pooled(8192) + counts(64) + bcount(256)
    float* pooled = (float*)alloc((8192 + 64 + 256) * 4);
    int* counts = (int*)(pooled + 8192);
    int* bcount = (int*)(pooled + 8192 + 64);

    const int TB = 256;
    int gGemm = (N + GBM - 1) / GBM;
    int gWave = (N + 3) / 4;

    hipMemsetAsync(pooled, 0, (8192 + 64 + 256) * 4, stream);
    transpose_w2<<<128, TB, 0, stream>>>(W1, W2, Wt1, Wt2);

    // CSR build (shared by both layers)
    bucket_hist<<<(E + 4095) / 4096, TB, 0, stream>>>(ei, bcount, E);
    bucket_scan<<<1, TB, 0, stream>>>(bcount, ebase, bcur, offs, NB, N, E);
    bucket_scatter<<<(E + 16383) / 16384, 1024, 0, stream>>>(ei, bcur, pk, E);
    csr_build<<<NB, TB, 0, stream>>>(pk, ebase, offs, ssrc, N);

    // ---- layer 1 ----
    gemm_kernel<float><<<gGemm, TB, 0, stream>>>(x, Wt1, XLb, as1, ad1, a_src, a_dst, N);
    gat_node_kernel<<<gWave, TB, 0, stream>>>(XLb, a_src, a_dst, offs, ssrc, b1, Hb, N);

    // ---- layer 2 ----
    gemm_kernel<unsigned short><<<gGemm, TB, 0, stream>>>(Hb, Wt2, XLb, as2, ad2, a_src, a_dst, N);
    gat_node_kernel<<<gWave, TB, 0, stream>>>(XLb, a_src, a_dst, offs, ssrc, b2, Hb, N);

    // ---- pool + FC ----
    pool_kernel<<<(N + PB - 1) / PB, 128, 0, stream>>>(Hb, batch, pooled, counts, N);
    final_kernel<<<8, TB, 0, stream>>>(pooled, counts, fcw, fcb, out);
}

// Round 7
// 276.779 us; speedup vs baseline: 7.6524x; 1.1648x over previous
//
#include <hip/hip_runtime.h>
#include <hip/hip_bf16.h>

// SmallGAT R7: MFMA bf16 GEMM (W bf16, whole-K in LDS, fused att-dot epilogue).
// Bucket CSR, wave-per-node GAT, LDS pool unchanged from R6.

#define NEG_SLOPE 0.2f

typedef short bf16x8 __attribute__((ext_vector_type(8)));
typedef float f32x4 __attribute__((ext_vector_type(4)));

__device__ __forceinline__ float lrelu(float x) { return x > 0.f ? x : NEG_SLOPE * x; }
__device__ __forceinline__ float bf2f(unsigned short u) { return __uint_as_float(((unsigned)u) << 16); }
__device__ __forceinline__ unsigned short f2bf(float f) {
    unsigned x = __float_as_uint(f);
    return (unsigned short)((x + 0x7fffu + ((x >> 16) & 1u)) >> 16);  // RNE
}

// ---------------- CSR build via dst-range buckets ----------------
__global__ __launch_bounds__(256) void bucket_hist(const int* __restrict__ ei, int* __restrict__ bcount, int E) {
    __shared__ int hist[256];
    int t = threadIdx.x;
    hist[t] = 0;
    __syncthreads();
    int eb = blockIdx.x * 4096;
#pragma unroll
    for (int i = 0; i < 16; ++i) {
        int e = eb + i * 256 + t;
        if (e < E) atomicAdd(&hist[ei[E + e] >> 8], 1);
    }
    __syncthreads();
    if (hist[t]) atomicAdd(&bcount[t], hist[t]);
}

__global__ __launch_bounds__(256) void bucket_scan(const int* __restrict__ bcount, int* __restrict__ ebase,
                                                   int* __restrict__ bcur, int* __restrict__ offs, int NB, int N, int E) {
    __shared__ int sc[256];
    int t = threadIdx.x;
    int cnt = (t < NB) ? bcount[t] : 0;
    sc[t] = cnt;
    __syncthreads();
    for (int off = 1; off < 256; off <<= 1) {
        int x = (t >= off) ? sc[t - off] : 0;
        __syncthreads();
        sc[t] += x;
        __syncthreads();
    }
    int excl = sc[t] - cnt;
    if (t < NB) {
        ebase[t] = excl;
        bcur[t] = excl;
    }
    if (t == NB - 1) ebase[NB] = sc[t];
    if (t == 0) offs[N] = E + N;
}

__global__ __launch_bounds__(1024) void bucket_scatter(const int* __restrict__ ei, int* __restrict__ bcur,
                                                       unsigned* __restrict__ pk, int E) {
    __shared__ int hist[256];
    __shared__ int base[256];
    int t = threadIdx.x;
    if (t < 256) hist[t] = 0;
    __syncthreads();
    int eb = blockIdx.x * 16384;
    int d[16];
#pragma unroll
    for (int i = 0; i < 16; ++i) {
        int e = eb + i * 1024 + t;
        if (e < E) {
            d[i] = ei[E + e];
            atomicAdd(&hist[d[i] >> 8], 1);
        } else {
            d[i] = -1;
        }
    }
    __syncthreads();
    if (t < 256) {
        int c = hist[t];
        base[t] = c ? atomicAdd(&bcur[t], c) : 0;
        hist[t] = 0;
    }
    __syncthreads();
#pragma unroll
    for (int i = 0; i < 16; ++i) {
        if (d[i] >= 0) {
            int s = ei[eb + i * 1024 + t];
            int bk = d[i] >> 8;
            int r = atomicAdd(&hist[bk], 1);
            pk[base[bk] + r] = ((unsigned)s << 8) | (unsigned)(d[i] & 255);
        }
    }
}

__global__ __launch_bounds__(256) void csr_build(const unsigned* __restrict__ pk, const int* __restrict__ ebase,
                                                 int* __restrict__ offs, int* __restrict__ ssrc, int N) {
    __shared__ int deg[256];
    __shared__ int curs[256];
    __shared__ int sc[256];
    int t = threadIdx.x;
    int b = blockIdx.x;
    deg[t] = 0;
    __syncthreads();
    int e0 = ebase[b], e1 = ebase[b + 1];
    for (int j = e0 + t; j < e1; j += 256) atomicAdd(&deg[pk[j] & 255], 1);
    __syncthreads();
    int nb0 = b * 256;
    int ncount = min(256, N - nb0);
    int v = (t < ncount) ? deg[t] + 1 : 0;
    sc[t] = v;
    __syncthreads();
    for (int off = 1; off < 256; off <<= 1) {
        int x = (t >= off) ? sc[t - off] : 0;
        __syncthreads();
        sc[t] += x;
        __syncthreads();
    }
    int nbase = e0 + b * 256;
    if (t < ncount) {
        int o = nbase + sc[t] - v;
        offs[nb0 + t] = o;
        ssrc[o] = nb0 + t;   // self-loop first
        curs[t] = o + 1;
    }
    __syncthreads();
    for (int j = e0 + t; j < e1; j += 256) {
        unsigned e = pk[j];
        int pos = atomicAdd(&curs[e & 255], 1);
        ssrc[pos] = (int)(e >> 8);
    }
}

// ---------------- W -> bf16 convert (no transpose: MFMA B-frag reads W rows) ----------------
__global__ void w_convert(const float* __restrict__ W1, const float* __restrict__ W2,
                          unsigned short* __restrict__ Wb1, unsigned short* __restrict__ Wb2) {
    int i = blockIdx.x * 256 + threadIdx.x;
    if (i < 16384) Wb1[i] = f2bf(W1[i]);
    else if (i < 32768) Wb2[i - 16384] = f2bf(W2[i - 16384]);
}

// ---------------- MFMA GEMM: out[m][n] = sum_k A[m][k]*W[n][k], fused att-dot epilogue ----------------
// block: 256 thr = 4 waves, BM=64 rows. LDS: W 128x136 bf16 (34.8KB) + A 64x136 bf16 (17.4KB).
// wave w: rows w*16..+15. 8 n-tiles x 4 k-steps of mfma_f32_16x16x32_bf16.
#define LDW 136
template <typename T>
__global__ __launch_bounds__(256) void gemm_kernel(const T* __restrict__ A, const unsigned short* __restrict__ Wb,
                                                   unsigned short* __restrict__ out,
                                                   const float* __restrict__ att_s, const float* __restrict__ att_d,
                                                   float* __restrict__ a_src, float* __restrict__ a_dst, int M) {
    __shared__ unsigned short Ws[128 * LDW];
    __shared__ unsigned short As[64 * LDW];
    int tid = threadIdx.x;
    int m0 = blockIdx.x * 64;
    // stage W: 2048 uint4 slots
#pragma unroll
    for (int i = 0; i < 8; ++i) {
        int slot = i * 256 + tid;
        int r = slot >> 4;
        int c8 = (slot & 15) << 3;
        uint4 u = *(const uint4*)(Wb + r * 128 + c8);
        *(uint4*)(&Ws[r * LDW + c8]) = u;
    }
    // stage A (convert fp32 -> bf16 if needed)
    if constexpr (sizeof(T) == 4) {
#pragma unroll
        for (int i = 0; i < 8; ++i) {
            int slot = i * 256 + tid;
            int r = slot >> 5;
            int c4 = (slot & 31) << 2;
            int m = m0 + r;
            float4 v = make_float4(0.f, 0.f, 0.f, 0.f);
            if (m < M) v = *(const float4*)((const float*)A + (size_t)m * 128 + c4);
            ushort4 w4;
            w4.x = f2bf(v.x); w4.y = f2bf(v.y); w4.z = f2bf(v.z); w4.w = f2bf(v.w);
            *(ushort4*)(&As[r * LDW + c4]) = w4;
        }
    } else {
#pragma unroll
        for (int i = 0; i < 4; ++i) {
            int slot = i * 256 + tid;
            int r = slot >> 4;
            int c8 = (slot & 15) << 3;
            int m = m0 + r;
            uint4 u = make_uint4(0, 0, 0, 0);
            if (m < M) u = *(const uint4*)((const unsigned short*)A + (size_t)m * 128 + c8);
            *(uint4*)(&As[r * LDW + c8]) = u;
        }
    }
    __syncthreads();
    int w = tid >> 6, l = tid & 63;
    int lr = l & 15;            // A-row / B-col within tile
    int lk = (l >> 4) << 3;     // k-offset 0/8/16/24
    f32x4 acc0 = {0.f, 0.f, 0.f, 0.f}, acc1 = acc0, acc2 = acc0, acc3 = acc0;
    f32x4 acc4 = acc0, acc5 = acc0, acc6 = acc0, acc7 = acc0;
    int arow = (w * 16 + lr) * LDW;
#pragma unroll
    for (int ks = 0; ks < 4; ++ks) {
        int kb = ks * 32 + lk;
        bf16x8 af = *(const bf16x8*)(&As[arow + kb]);
#define MSTEP(i) { bf16x8 bfv = *(const bf16x8*)(&Ws[((i) * 16 + lr) * LDW + kb]); \
                   acc##i = __builtin_amdgcn_mfma_f32_16x16x32_bf16(af, bfv, acc##i, 0, 0, 0); }
        MSTEP(0) MSTEP(1) MSTEP(2) MSTEP(3) MSTEP(4) MSTEP(5) MSTEP(6) MSTEP(7)
#undef MSTEP
    }
    // C/D layout: col = lr, row-in-tile = (l>>4)*4 + j
    int rbase = m0 + w * 16 + ((l >> 4) << 2);
    // store bf16 out
#pragma unroll
    for (int j = 0; j < 4; ++j) {
        int m = rbase + j;
        if (m < M) {
            unsigned ob = (unsigned)m * 128 + (unsigned)lr;
            out[ob + 0]   = f2bf(acc0[j]);
            out[ob + 16]  = f2bf(acc1[j]);
            out[ob + 32]  = f2bf(acc2[j]);
            out[ob + 48]  = f2bf(acc3[j]);
            out[ob + 64]  = f2bf(acc4[j]);
            out[ob + 80]  = f2bf(acc5[j]);
            out[ob + 96]  = f2bf(acc6[j]);
            out[ob + 112] = f2bf(acc7[j]);
        }
    }
    // fused attention dots (fp32 acc, pre-rounding)
    float as0 = att_s[lr], as1 = att_s[16 + lr], as2 = att_s[32 + lr], as3 = att_s[48 + lr];
    float as4 = att_s[64 + lr], as5 = att_s[80 + lr], as6 = att_s[96 + lr], as7 = att_s[112 + lr];
    float ad0 = att_d[lr], ad1 = att_d[16 + lr], ad2 = att_d[32 + lr], ad3 = att_d[48 + lr];
    float ad4 = att_d[64 + lr], ad5 = att_d[80 + lr], ad6 = att_d[96 + lr], ad7 = att_d[112 + lr];
#pragma unroll
    for (int j = 0; j < 4; ++j) {
        float ps0 = acc0[j] * as0 + acc1[j] * as1 + acc2[j] * as2 + acc3[j] * as3;
        float pd0 = acc0[j] * ad0 + acc1[j] * ad1 + acc2[j] * ad2 + acc3[j] * ad3;
        float ps1 = acc4[j] * as4 + acc5[j] * as5 + acc6[j] * as6 + acc7[j] * as7;
        float pd1 = acc4[j] * ad4 + acc5[j] * ad5 + acc6[j] * ad6 + acc7[j] * ad7;
#pragma unroll
        for (int off = 1; off < 16; off <<= 1) {
            ps0 += __shfl_xor(ps0, off);
            pd0 += __shfl_xor(pd0, off);
            ps1 += __shfl_xor(ps1, off);
            pd1 += __shfl_xor(pd1, off);
        }
        if (lr == 0) {
            int m = rbase + j;
            if (m < M) {
                a_src[m * 2 + 0] = ps0;
                a_dst[m * 2 + 0] = pd0;
                a_src[m * 2 + 1] = ps1;
                a_dst[m * 2 + 1] = pd1;
            }
        }
    }
}

// ---------------- fused per-node softmax + aggregate (wave per node) ----------------
#define MAXD 128
__global__ __launch_bounds__(256) void gat_node_kernel(const unsigned short* __restrict__ XLb,
                                                       const float* __restrict__ a_src, const float* __restrict__ a_dst,
                                                       const int* __restrict__ offs, const int* __restrict__ ssrc,
                                                       const float* __restrict__ bias,
                                                       unsigned short* __restrict__ out, int N) {
    __shared__ float coeff[4][2][MAXD];
    __shared__ int srcs[4][MAXD];
    int t = threadIdx.x;
    int w = t >> 6, l = t & 63;
    int n = blockIdx.x * 4 + w;
    if (n >= N) return;
    int h = l >> 5, sl = l & 31;
    int c = 2 * l;
    int j0 = offs[n], j1 = offs[n + 1];
    int deg = j1 - j0;
    float ad = a_dst[n * 2 + h];
    float acc0 = 0.f, acc1 = 0.f;
    if (deg <= MAXD) {
        float m = -1e30f;
        for (int k = sl; k < deg; k += 32) {
            int s = ssrc[j0 + k];
            if (h == 0) srcs[w][k] = s;
            float al = lrelu(a_src[s * 2 + h] + ad);
            coeff[w][h][k] = al;
            m = fmaxf(m, al);
        }
#pragma unroll
        for (int off = 16; off > 0; off >>= 1) m = fmaxf(m, __shfl_xor(m, off));
        float sum = 0.f;
        for (int k = sl; k < deg; k += 32) {
            float e = __expf(coeff[w][h][k] - m);
            coeff[w][h][k] = e;
            sum += e;
        }
#pragma unroll
        for (int off = 16; off > 0; off >>= 1) sum += __shfl_xor(sum, off);
        float inv = 1.f / fmaxf(sum, 1e-16f);
        int j = 0;
        for (; j + 1 < deg; j += 2) {
            float c0 = coeff[w][h][j] * inv;
            float c1 = coeff[w][h][j + 1] * inv;
            unsigned s0 = (unsigned)srcs[w][j];
            unsigned s1 = (unsigned)srcs[w][j + 1];
            unsigned u0 = *(const unsigned*)(XLb + (s0 << 7) + c);
            unsigned u1 = *(const unsigned*)(XLb + (s1 << 7) + c);
            acc0 += c0 * __uint_as_float(u0 << 16) + c1 * __uint_as_float(u1 << 16);
            acc1 += c0 * __uint_as_float(u0 & 0xffff0000u) + c1 * __uint_as_float(u1 & 0xffff0000u);
        }
        if (j < deg) {
            float c0 = coeff[w][h][j] * inv;
            unsigned s0 = (unsigned)srcs[w][j];
            unsigned u0 = *(const unsigned*)(XLb + (s0 << 7) + c);
            acc0 += c0 * __uint_as_float(u0 << 16);
            acc1 += c0 * __uint_as_float(u0 & 0xffff0000u);
        }
    } else {
        float m = -1e30f;
        for (int k = sl; k < deg; k += 32) {
            int s = ssrc[j0 + k];
            m = fmaxf(m, lrelu(a_src[s * 2 + h] + ad));
        }
#pragma unroll
        for (int off = 16; off > 0; off >>= 1) m = fmaxf(m, __shfl_xor(m, off));
        float sum = 0.f;
        for (int k = sl; k < deg; k += 32) {
            int s = ssrc[j0 + k];
            sum += __expf(lrelu(a_src[s * 2 + h] + ad) - m);
        }
#pragma unroll
        for (int off = 16; off > 0; off >>= 1) sum += __shfl_xor(sum, off);
        float inv = 1.f / fmaxf(sum, 1e-16f);
        for (int j = 0; j < deg; ++j) {
            unsigned s = (unsigned)ssrc[j0 + j];
            float cc = __expf(lrelu(a_src[s * 2 + h] + ad) - m) * inv;
            unsigned u0 = *(const unsigned*)(XLb + (s << 7) + c);
            acc0 += cc * __uint_as_float(u0 << 16);
            acc1 += cc * __uint_as_float(u0 & 0xffff0000u);
        }
    }
    float o0 = fmaxf(acc0 + bias[c], 0.f);
    float o1 = fmaxf(acc1 + bias[c + 1], 0.f);
    *(unsigned*)(out + ((unsigned)n << 7) + c) = (unsigned)f2bf(o0) | ((unsigned)f2bf(o1) << 16);
}

// ---------------- pooling (LDS-staged) + FC ----------------
#define PB 128
__global__ __launch_bounds__(128) void pool_kernel(const unsigned short* __restrict__ Hb,
                                                   const int* __restrict__ batch,
                                                   float* __restrict__ pooled, int* __restrict__ counts, int N) {
    __shared__ unsigned short Hs[PB * 128];
    __shared__ int bs[PB];
    int t = threadIdx.x;
    int base = blockIdx.x * PB;
    int lim = min(PB, N - base);
#pragma unroll
    for (int i = 0; i < 16; ++i) {
        int slot = i * 128 + t;
        int r = slot >> 4;
        int c8 = (slot & 15) << 3;
        uint4 u = make_uint4(0, 0, 0, 0);
        int n0 = base + r;
        if (n0 < N) u = *(const uint4*)(Hb + (size_t)n0 * 128 + c8);
        *(uint4*)(&Hs[r * 128 + c8]) = u;
    }
    if (t < lim) bs[t] = batch[base + t];
    __syncthreads();
    float acc = 0.f;
    int cur = bs[0];
    int runstart = 0;
    for (int i = 0; i < lim; ++i) {
        int g = bs[i];
        if (g != cur) {
            atomicAdd(&pooled[cur * 128 + t], acc);
            if (t == 0) atomicAdd(&counts[cur], i - runstart);
            cur = g;
            acc = 0.f;
            runstart = i;
        }
        acc += bf2f(Hs[i * 128 + t]);
    }
    atomicAdd(&pooled[cur * 128 + t], acc);
    if (t == 0) atomicAdd(&counts[cur], lim - runstart);
}

__global__ void final_kernel(const float* __restrict__ pooled, const int* __restrict__ counts,
                             const float* __restrict__ fc_w, const float* __restrict__ fc_b,
                             float* __restrict__ out) {
    int idx = blockIdx.x * 256 + threadIdx.x;
    if (idx >= 64 * 32) return;
    int g = idx >> 5, k = idx & 31;
    float invc = 1.f / fmaxf((float)counts[g], 1.f);
    float s = 0.f;
#pragma unroll 4
    for (int c = 0; c < 128; ++c) s += pooled[g * 128 + c] * fc_w[k * 128 + c];
    out[idx] = s * invc + fc_b[k];
}

// ---------------- host ----------------
extern "C" void kernel_launch(void* const* d_in, const int* in_sizes, int n_in,
                              void* d_out, int out_size, void* d_ws, size_t ws_size,
                              hipStream_t stream) {
    const float* x = (const float*)d_in[0];
    const int* ei = (const int*)d_in[1];
    const int* batch = (const int*)d_in[2];
    const float* W1 = (const float*)d_in[3];
    const float* as1 = (const float*)d_in[4];
    const float* ad1 = (const float*)d_in[5];
    const float* b1 = (const float*)d_in[6];
    const float* W2 = (const float*)d_in[7];
    const float* as2 = (const float*)d_in[8];
    const float* ad2 = (const float*)d_in[9];
    const float* b2 = (const float*)d_in[10];
    const float* fcw = (const float*)d_in[11];
    const float* fcb = (const float*)d_in[12];
    float* out = (float*)d_out;

    const int N = in_sizes[0] / 128;  // 50000
    const int E = in_sizes[1] / 2;    // 800000
    const int EN = E + N;
    const int NB = (N + 255) >> 8;    // 196 buckets

    char* p = (char*)d_ws;
    auto alloc = [&](size_t bytes) -> char* {
        char* r = p;
        p += (bytes + 255) & ~(size_t)255;
        return r;
    };
    unsigned short* XLb = (unsigned short*)alloc((size_t)N * 128 * 2);
    unsigned short* Hb = (unsigned short*)alloc((size_t)N * 128 * 2);
    float* a_src = (float*)alloc((size_t)N * 2 * 4);
    float* a_dst = (float*)alloc((size_t)N * 2 * 4);
    int* offs = (int*)alloc((size_t)(N + 1) * 4);
    int* ssrc = (int*)alloc((size_t)EN * 4);
    unsigned* pk = (unsigned*)alloc((size_t)E * 4);
    int* ebase = (int*)alloc((size_t)(NB + 1) * 4);
    int* bcur = (int*)alloc((size_t)NB * 4);
    unsigned short* Wb1 = (unsigned short*)alloc(16384 * 2);
    unsigned short* Wb2 = (unsigned short*)alloc(16384 * 2);
    // zeroed region: pooled(8192) + counts(64) + bcount(256)
    float* pooled = (float*)alloc((8192 + 64 + 256) * 4);
    int* counts = (int*)(pooled + 8192);
    int* bcount = (int*)(pooled + 8192 + 64);

    const int TB = 256;
    int gGemm = (N + 63) / 64;
    int gWave = (N + 3) / 4;

    hipMemsetAsync(pooled, 0, (8192 + 64 + 256) * 4, stream);
    w_convert<<<128, TB, 0, stream>>>(W1, W2, Wb1, Wb2);

    // CSR build (shared by both layers)
    bucket_hist<<<(E + 4095) / 4096, TB, 0, stream>>>(ei, bcount, E);
    bucket_scan<<<1, TB, 0, stream>>>(bcount, ebase, bcur, offs, NB, N, E);
    bucket_scatter<<<(E + 16383) / 16384, 1024, 0, stream>>>(ei, bcur, pk, E);
    csr_build<<<NB, TB, 0, stream>>>(pk, ebase, offs, ssrc, N);

    // ---- layer 1 ----
    gemm_kernel<float><<<gGemm, TB, 0, stream>>>(x, Wb1, XLb, as1, ad1, a_src, a_dst, N);
    gat_node_kernel<<<gWave, TB, 0, stream>>>(XLb, a_src, a_dst, offs, ssrc, b1, Hb, N);

    // ---- layer 2 ----
    gemm_kernel<unsigned short><<<gGemm, TB, 0, stream>>>(Hb, Wb2, XLb, as2, ad2, a_src, a_dst, N);
    gat_node_kernel<<<gWave, TB, 0, stream>>>(XLb, a_src, a_dst, offs, ssrc, b2, Hb, N);

    // ---- pool + FC ----
    pool_kernel<<<(N + PB - 1) / PB, 128, 0, stream>>>(Hb, batch, pooled, counts, N);
    final_kernel<<<8, TB, 0, stream>>>(pooled, counts, fcw, fcb, out);
}